// Round 18
// baseline (140.682 us; speedup 1.0000x reference)
//
#include <hip/hip_runtime.h>
#include <hip/hip_bf16.h>

typedef __hip_bfloat16 bf16;
typedef short s8v __attribute__((ext_vector_type(8)));
typedef float f4v __attribute__((ext_vector_type(4)));
typedef float f2v __attribute__((ext_vector_type(2)));

#define B   128
#define N   2000
#define S   64
#define CAP 128          // max neighbors per row (mean ~65, 8-sigma safe)
#define JT  16           // j-rows per block in k_x2g
#define JG  8            // j-rows per block in k_gather
#define XROW 1088        // S*17

__device__ inline ushort bfb(float v) {
    union { __hip_bfloat16 h; ushort u; } c; c.h = __float2bfloat16(v); return c.u;
}

// ------ k_prep0: rowsum (blk<N) + pack w_gc1/w_gc2/w_fc1 frags (blk>=N) ----
__global__ __launch_bounds__(256) void k_prep0(const float* __restrict__ adj,
                                               float* __restrict__ d,
                                               const float* __restrict__ w1,
                                               const float* __restrict__ w2,
                                               const float* __restrict__ wfc1,
                                               uint4* __restrict__ wf1,
                                               uint4* __restrict__ wf2,
                                               uint4* __restrict__ wf3) {
    int blk = blockIdx.x;
    if (blk < N) {
        int m = blk;
        const float* row = adj + (size_t)m * N;
        float s = 0.f;
        for (int c = threadIdx.x; c < N; c += 256) s += row[c];
        for (int o = 32; o > 0; o >>= 1) s += __shfl_down(s, o);
        __shared__ float red[4];
        int wave = threadIdx.x >> 6;
        if ((threadIdx.x & 63) == 0) red[wave] = s;
        __syncthreads();
        if (threadIdx.x == 0)
            d[m] = rsqrtf(red[0] + red[1] + red[2] + red[3] + 1.0f);
    } else if (blk < N + 36) {
        int blk2 = blk - N;
        if (blk2 < 4) {
            int e = blk2 * 256 + threadIdx.x;          // 0..1023
            int ct = e >> 6, l = e & 63;
            int kg = l >> 4, ch = ct * 16 + (l & 15);
            ushort h[8];
#pragma unroll
            for (int j = 0; j < 8; ++j) {
                int f = kg * 8 + j;
                h[j] = (f < 16) ? bfb(w1[f * 256 + ch]) : (ushort)0;
            }
            uint4 r;
            r.x = h[0] | ((uint)h[1] << 16);
            r.y = h[2] | ((uint)h[3] << 16);
            r.z = h[4] | ((uint)h[5] << 16);
            r.w = h[6] | ((uint)h[7] << 16);
            wf1[e] = r;
        } else {
            int e = (blk2 - 4) * 256 + threadIdx.x;    // 0..8191
            int l = e & 63;
            int kc = (e >> 6) & 7;
            int nt = e >> 9;
            int col = l & 15, kg = l >> 4;
            ushort h[8];
#pragma unroll
            for (int i = 0; i < 8; ++i) {
                int k = kc * 32 + kg * 8 + i;
                h[i] = bfb(w2[k * 256 + nt * 16 + col]);
            }
            uint4 r;
            r.x = h[0] | ((uint)h[1] << 16);
            r.y = h[2] | ((uint)h[3] << 16);
            r.z = h[4] | ((uint)h[5] << 16);
            r.w = h[6] | ((uint)h[7] << 16);
            wf2[e] = r;
        }
    } else {
        // pack w_fc1 [1024 x 512] -> B-frags: e = (nt*32 + kc)*64 + l
        int e = (blk - N - 36) * 256 + threadIdx.x;    // 0..65535
        int l = e & 63;
        int kc = (e >> 6) & 31;
        int nt = e >> 11;
        int col = l & 15, kg = l >> 4;
        ushort h[8];
#pragma unroll
        for (int i = 0; i < 8; ++i) {
            int k = kc * 32 + kg * 8 + i;
            h[i] = bfb(wfc1[(size_t)k * 512 + nt * 16 + col]);
        }
        uint4 r;
        r.x = h[0] | ((uint)h[1] << 16);
        r.y = h[2] | ((uint)h[3] << 16);
        r.z = h[4] | ((uint)h[5] << 16);
        r.w = h[6] | ((uint)h[7] << 16);
        wf3[e] = r;
    }
}

// ---- k_prep1: CSR x4/block (blk<500) + extract (500..627) + fc0s (>=628) --
__global__ __launch_bounds__(256) void k_prep1(const float* __restrict__ adj,
                                               const float* __restrict__ d,
                                               const float* __restrict__ x,
                                               int* __restrict__ cnt,
                                               int* __restrict__ idx,
                                               float* __restrict__ val,
                                               int* __restrict__ sid,
                                               int* __restrict__ sid_last,
                                               uint4* __restrict__ feA,
                                               const float* __restrict__ w0,
                                               const float* __restrict__ b0,
                                               float* __restrict__ hp0,
                                               float* __restrict__ mu0,
                                               float* __restrict__ rstd0) {
    int blk = blockIdx.x;
    if (blk < 500) {
        int m = blk * 4 + (threadIdx.x >> 6);
        int lane = threadIdx.x & 63;
        const float* row = adj + (size_t)m * N;
        float dm = d[m];
        int base = 0;
        for (int c0 = 0; c0 < N; c0 += 64) {
            int c = c0 + lane;
            float a = 0.f;
            if (c < N) { a = row[c]; if (c == m) a += 1.0f; }
            bool pred = (a != 0.f);
            unsigned long long mask = __ballot(pred);
            int pos = base + __popcll(mask & ((1ull << lane) - 1ull));
            if (pred && pos < CAP) {
                idx[m * CAP + pos] = c;
                val[m * CAP + pos] = dm * d[c] * a;
            }
            base += (int)__popcll(mask);
        }
        if (lane == 0) cnt[m] = base < CAP ? base : CAP;
    } else if (blk < 500 + B) {
        int b = blk - 500, tid = threadIdx.x;
        const float* xb = x + (size_t)b * XROW;
        __shared__ float dss_sh[63];
        __shared__ float fe_sh[64][16];
        if (tid < S - 1) {
            int s_ = (int)xb[tid * 17 + 15];
            sid[b * (S - 1) + tid] = s_;
            dss_sh[tid] = d[s_];
        }
        if (tid == S - 1) sid_last[b] = (int)xb[(S - 1) * 17 + 15];
        if (tid >= 240 && tid < 256) fe_sh[63][tid - 240] = 0.f;   // zero pad
        __syncthreads();
        for (int i = tid; i < (S - 1) * 16; i += 256) {
            int t = i >> 4, f = i & 15;
            fe_sh[t][f] = dss_sh[t] * xb[t * 17 + (f < 15 ? f : 16)];
        }
        __syncthreads();
        if (tid < 128) {
            int kc = tid >> 6, l = tid & 63;
            int f = l & 15, tg = l >> 4;
            ushort h[8];
#pragma unroll
            for (int j = 0; j < 8; ++j)
                h[j] = bfb(fe_sh[kc * 32 + tg * 8 + j][f]);
            uint4 r;
            r.x = h[0] | ((uint)h[1] << 16);
            r.y = h[2] | ((uint)h[3] << 16);
            r.z = h[4] | ((uint)h[5] << 16);
            r.w = h[6] | ((uint)h[7] << 16);
            feA[(b * 2 + kc) * 64 + l] = r;
        }
    } else {
        // fused fc0 + batch stats: block = 2 channels x 128 batch
        int tid = threadIdx.x;
        int c = tid >> 7, b = tid & 127;
        int o = (blk - 500 - B) * 2 + c;
        const float* xr = x + (size_t)b * XROW + (S - 1) * 17;
        float acc = b0[o];
#pragma unroll
        for (int f = 0; f < 15; ++f) acc += xr[f] * w0[f * 512 + o];
        hp0[b * 512 + o] = acc;
        float s = acc, s2 = acc * acc;
        for (int off = 32; off > 0; off >>= 1) {
            s += __shfl_down(s, off);
            s2 += __shfl_down(s2, off);
        }
        __shared__ float rs[4], rs2[4];
        int wv = tid >> 6;
        if ((tid & 63) == 0) { rs[wv] = s; rs2[wv] = s2; }
        __syncthreads();
        if ((tid & 127) == 0) {
            float S1 = rs[c * 2] + rs[c * 2 + 1];
            float S2 = rs2[c * 2] + rs2[c * 2 + 1];
            float m = S1 * (1.f / B);
            float var = S2 * (1.f / B) - m * m;
            mu0[o] = m;
            rstd0[o] = rsqrtf(var + 1e-5f);
        }
    }
}

// ---------------- kernel 4: X1[b,p,:] = relu((Ahat X)[b,p] @ w1 + b1) ------
__global__ __launch_bounds__(256) void k_x1(const float* __restrict__ adj,
                                            const float* __restrict__ d,
                                            const int* __restrict__ sid,
                                            const uint4* __restrict__ feA,
                                            const uint4* __restrict__ wfrag,
                                            const float* __restrict__ b1,
                                            unsigned char* __restrict__ X1) {
    __shared__ int sv[64];
    __shared__ float b1s[256];
    __shared__ __align__(16) union SU {
        ushort Ylds[64][40];     // 80B rows (phase 1 -> phase 2 hand-off)
        uint   Xs[4][16][68];    // epilogue transpose tile (after Ylds dead)
    } su;
    int b = blockIdx.y, p0 = blockIdx.x * 64, tid = threadIdx.x;
    b1s[tid] = b1[tid];
    if (tid < 63) sv[tid] = sid[b * 63 + tid];
    if (tid == 63) sv[63] = 0;
    __syncthreads();

    int l = tid & 63, wv = tid >> 6;
    int lm = l & 15, lg = l >> 4;
    int pt = p0 + wv * 16;
    int pcol = pt + lm;
    bool pv = (pcol < N);
    int pc = pv ? pcol : 0;

    s8v a1_0 = *(const s8v*)&feA[(b * 2 + 0) * 64 + l];
    s8v a1_1 = *(const s8v*)&feA[(b * 2 + 1) * 64 + l];

    int ss[16];
#pragma unroll
    for (int q = 0; q < 16; ++q)
        ss[q] = sv[(q >> 3) * 32 + lg * 8 + (q & 7)];
    float av[16];
#pragma unroll
    for (int q = 0; q < 16; ++q)
        av[q] = adj[(size_t)ss[q] * N + pc];
#pragma unroll
    for (int q = 0; q < 16; ++q) {
        av[q] = pv ? av[q] : 0.f;
        if (pcol == ss[q]) av[q] += 1.0f;
    }
    ushort h[16];
#pragma unroll
    for (int q = 0; q < 16; ++q) h[q] = bfb(av[q]);
    s8v b1f, b2f;
    {
        uint4 t0, t1;
        t0.x = h[0] | ((uint)h[1] << 16);  t0.y = h[2] | ((uint)h[3] << 16);
        t0.z = h[4] | ((uint)h[5] << 16);  t0.w = h[6] | ((uint)h[7] << 16);
        t1.x = h[8] | ((uint)h[9] << 16);  t1.y = h[10] | ((uint)h[11] << 16);
        t1.z = h[12] | ((uint)h[13] << 16); t1.w = h[14] | ((uint)h[15] << 16);
        b1f = *(s8v*)&t0; b2f = *(s8v*)&t1;
    }
    f4v D1 = (f4v){0.f, 0.f, 0.f, 0.f};
    D1 = __builtin_amdgcn_mfma_f32_16x16x32_bf16(a1_0, b1f, D1, 0, 0, 0);
    D1 = __builtin_amdgcn_mfma_f32_16x16x32_bf16(a1_1, b2f, D1, 0, 0, 0);
    float dp = d[pc] * (pv ? 1.f : 0.f);
    uint2 pk;
    pk.x = bfb(D1[0] * dp) | ((uint)bfb(D1[1] * dp) << 16);
    pk.y = bfb(D1[2] * dp) | ((uint)bfb(D1[3] * dp) << 16);
    *(uint2*)&su.Ylds[wv * 16 + lm][lg * 4] = pk;
    *(uint2*)&su.Ylds[wv * 16 + lm][16 + lg * 4] = make_uint2(0u, 0u);  // K-pad
    __syncthreads();

    s8v yf = *(const s8v*)&su.Ylds[wv * 16 + lm][lg * 8];   // B = Y^T frag
    __syncthreads();   // all yf read before Xs overwrites Ylds (union)
    f4v acc2[16];
#pragma unroll
    for (int ct = 0; ct < 16; ++ct) acc2[ct] = (f4v){0.f, 0.f, 0.f, 0.f};
#pragma unroll
    for (int ct = 0; ct < 16; ++ct) {
        s8v wfv = *(const s8v*)&wfrag[ct * 64 + l];         // A = W^T frag
        acc2[ct] = __builtin_amdgcn_mfma_f32_16x16x32_bf16(wfv, yf, acc2[ct], 0, 0, 0);
    }
#pragma unroll
    for (int ct = 0; ct < 16; ++ct) {
        float4 bz = *(float4*)&b1s[ct * 16 + lg * 4];
        float v0 = acc2[ct][0] + bz.x; v0 = v0 > 0.f ? v0 : 0.f;
        float v1 = acc2[ct][1] + bz.y; v1 = v1 > 0.f ? v1 : 0.f;
        float v2 = acc2[ct][2] + bz.z; v2 = v2 > 0.f ? v2 : 0.f;
        float v3 = acc2[ct][3] + bz.w; v3 = v3 > 0.f ? v3 : 0.f;
        uint pk8 = (uint)__builtin_amdgcn_cvt_pk_fp8_f32(v0, v1, 0, false);
        pk8 = (uint)__builtin_amdgcn_cvt_pk_fp8_f32(v2, v3, (int)pk8, true);
        su.Xs[wv][lm][ct * 4 + lg] = pk8;
    }
    __syncthreads();
    {
        uint4* dstb = (uint4*)((uint*)X1 + ((size_t)b * N + p0 + wv * 16) * 64);
#pragma unroll
        for (int i = 0; i < 4; ++i) {
            int g = l + 64 * i;
            int r = g >> 4, c4 = g & 15;
            if (p0 + wv * 16 + r < N)
                dstb[g] = *(uint4*)&su.Xs[wv][r][c4 * 4];
        }
    }
}

// ---------------- kernel 5a: k_gather — fp8 agg out, 4-deep prefetch -------
__global__ __launch_bounds__(256) void k_gather(const int* __restrict__ cnt,
                                                const int* __restrict__ idxA,
                                                const float* __restrict__ valA,
                                                const int* __restrict__ sid_last,
                                                const unsigned char* __restrict__ X1,
                                                unsigned char* __restrict__ aggG) {
    __shared__ int   nns[JG];
    __shared__ int   ncn_s[JG];
    __shared__ int   nidx[JG][CAP];
    __shared__ float nval[JG][CAP];
    int b = blockIdx.y, j0 = blockIdx.x * JG, tid = threadIdx.x;
    int m = sid_last[b];
    int cj = cnt[m];
    if (tid < JG) {
        int j = j0 + tid;
        int n = idxA[m * CAP + (j < cj ? j : 0)];
        nns[tid] = n;
        ncn_s[tid] = (j < cj) ? cnt[n] : 0;
    }
    __syncthreads();
    for (int i = tid; i < JG * CAP; i += 256) {
        int jj = i >> 7, k = i & (CAP - 1);
        int n = nns[jj], c = ncn_s[jj];
        nidx[jj][k] = (k < c) ? idxA[n * CAP + k] : 0;
        nval[jj][k] = (k < c) ? valA[n * CAP + k] : 0.f;
    }
    __syncthreads();
    int lane = tid & 63;
    int w = __builtin_amdgcn_readfirstlane(tid >> 6);
    int la = w * 2, lb = la + 1;
    const uint* X1bl = (const uint*)X1 + (size_t)b * N * 64 + lane;
    int cA = ncn_s[la], cB = ncn_s[lb];
    int cmax = cA > cB ? cA : cB;
    float aA0 = 0.f, aA1 = 0.f, aA2 = 0.f, aA3 = 0.f;
    float aB0 = 0.f, aB1 = 0.f, aB2 = 0.f, aB3 = 0.f;
    if (cmax > 0) {
        uint uA0, uA1, uA2, uA3, uB0, uB1, uB2, uB3;
        float vA0, vA1, vA2, vA3, vB0, vB1, vB2, vB3;
        uA0 = X1bl[(size_t)nidx[la][0] * 64]; vA0 = nval[la][0];
        uA1 = X1bl[(size_t)nidx[la][1] * 64]; vA1 = nval[la][1];
        uA2 = X1bl[(size_t)nidx[la][2] * 64]; vA2 = nval[la][2];
        uA3 = X1bl[(size_t)nidx[la][3] * 64]; vA3 = nval[la][3];
        uB0 = X1bl[(size_t)nidx[lb][0] * 64]; vB0 = nval[lb][0];
        uB1 = X1bl[(size_t)nidx[lb][1] * 64]; vB1 = nval[lb][1];
        uB2 = X1bl[(size_t)nidx[lb][2] * 64]; vB2 = nval[lb][2];
        uB3 = X1bl[(size_t)nidx[lb][3] * 64]; vB3 = nval[lb][3];
        int c4 = (cmax + 3) & ~3;
        for (int k = 0; k < c4; k += 4) {
            uint cA0 = uA0, cA1 = uA1, cA2 = uA2, cA3 = uA3;
            uint cB0 = uB0, cB1 = uB1, cB2 = uB2, cB3 = uB3;
            float wA0 = vA0, wA1 = vA1, wA2 = vA2, wA3 = vA3;
            float wB0 = vB0, wB1 = vB1, wB2 = vB2, wB3 = vB3;
            int k4 = k + 4; k4 = k4 < CAP ? k4 : CAP - 1;
            int k5 = k + 5; k5 = k5 < CAP ? k5 : CAP - 1;
            int k6 = k + 6; k6 = k6 < CAP ? k6 : CAP - 1;
            int k7 = k + 7; k7 = k7 < CAP ? k7 : CAP - 1;
            uA0 = X1bl[(size_t)nidx[la][k4] * 64]; vA0 = nval[la][k4];
            uA1 = X1bl[(size_t)nidx[la][k5] * 64]; vA1 = nval[la][k5];
            uA2 = X1bl[(size_t)nidx[la][k6] * 64]; vA2 = nval[la][k6];
            uA3 = X1bl[(size_t)nidx[la][k7] * 64]; vA3 = nval[la][k7];
            uB0 = X1bl[(size_t)nidx[lb][k4] * 64]; vB0 = nval[lb][k4];
            uB1 = X1bl[(size_t)nidx[lb][k5] * 64]; vB1 = nval[lb][k5];
            uB2 = X1bl[(size_t)nidx[lb][k6] * 64]; vB2 = nval[lb][k6];
            uB3 = X1bl[(size_t)nidx[lb][k7] * 64]; vB3 = nval[lb][k7];
            f2v lo, hi;
            lo = __builtin_amdgcn_cvt_pk_f32_fp8((int)cA0, false);
            hi = __builtin_amdgcn_cvt_pk_f32_fp8((int)cA0, true);
            aA0 += wA0 * lo.x; aA1 += wA0 * lo.y; aA2 += wA0 * hi.x; aA3 += wA0 * hi.y;
            lo = __builtin_amdgcn_cvt_pk_f32_fp8((int)cA1, false);
            hi = __builtin_amdgcn_cvt_pk_f32_fp8((int)cA1, true);
            aA0 += wA1 * lo.x; aA1 += wA1 * lo.y; aA2 += wA1 * hi.x; aA3 += wA1 * hi.y;
            lo = __builtin_amdgcn_cvt_pk_f32_fp8((int)cA2, false);
            hi = __builtin_amdgcn_cvt_pk_f32_fp8((int)cA2, true);
            aA0 += wA2 * lo.x; aA1 += wA2 * lo.y; aA2 += wA2 * hi.x; aA3 += wA2 * hi.y;
            lo = __builtin_amdgcn_cvt_pk_f32_fp8((int)cA3, false);
            hi = __builtin_amdgcn_cvt_pk_f32_fp8((int)cA3, true);
            aA0 += wA3 * lo.x; aA1 += wA3 * lo.y; aA2 += wA3 * hi.x; aA3 += wA3 * hi.y;
            lo = __builtin_amdgcn_cvt_pk_f32_fp8((int)cB0, false);
            hi = __builtin_amdgcn_cvt_pk_f32_fp8((int)cB0, true);
            aB0 += wB0 * lo.x; aB1 += wB0 * lo.y; aB2 += wB0 * hi.x; aB3 += wB0 * hi.y;
            lo = __builtin_amdgcn_cvt_pk_f32_fp8((int)cB1, false);
            hi = __builtin_amdgcn_cvt_pk_f32_fp8((int)cB1, true);
            aB0 += wB1 * lo.x; aB1 += wB1 * lo.y; aB2 += wB1 * hi.x; aB3 += wB1 * hi.y;
            lo = __builtin_amdgcn_cvt_pk_f32_fp8((int)cB2, false);
            hi = __builtin_amdgcn_cvt_pk_f32_fp8((int)cB2, true);
            aB0 += wB2 * lo.x; aB1 += wB2 * lo.y; aB2 += wB2 * hi.x; aB3 += wB2 * hi.y;
            lo = __builtin_amdgcn_cvt_pk_f32_fp8((int)cB3, false);
            hi = __builtin_amdgcn_cvt_pk_f32_fp8((int)cB3, true);
            aB0 += wB3 * lo.x; aB1 += wB3 * lo.y; aB2 += wB3 * hi.x; aB3 += wB3 * hi.y;
        }
    }
    uint pkA = (uint)__builtin_amdgcn_cvt_pk_fp8_f32(aA0, aA1, 0, false);
    pkA = (uint)__builtin_amdgcn_cvt_pk_fp8_f32(aA2, aA3, (int)pkA, true);
    uint pkB = (uint)__builtin_amdgcn_cvt_pk_fp8_f32(aB0, aB1, 0, false);
    pkB = (uint)__builtin_amdgcn_cvt_pk_fp8_f32(aB2, aB3, (int)pkB, true);
    uint* ag = (uint*)aggG;
    ag[((size_t)b * CAP + j0 + la) * 64 + lane] = pkA;
    ag[((size_t)b * CAP + j0 + lb) * 64 + lane] = pkB;
}

// ---------------- kernel 5b: k_x2g — fp8 agg in, MFMA + j-reduction --------
__global__ __launch_bounds__(256) void k_x2g(const int* __restrict__ cnt,
                                             const int* __restrict__ sid_last,
                                             const float* __restrict__ valA,
                                             const unsigned char* __restrict__ aggG,
                                             const uint4* __restrict__ w2f,
                                             const float* __restrict__ b2,
                                             float* __restrict__ gaggP) {
    __shared__ ushort agg[JT][264];   // 528B row stride (bf16, unpacked)
    __shared__ float vs[JT];
    int b = blockIdx.y, j0 = blockIdx.x * JT, tid = threadIdx.x;
    int m = sid_last[b];
    int cj = cnt[m];
    if (j0 >= cj) return;
    int nj = cj - j0; if (nj > JT) nj = JT;
    if (tid < JT) vs[tid] = (tid < nj) ? valA[m * CAP + j0 + tid] : 0.f;
    {
        const uint* src = (const uint*)aggG + ((size_t)b * CAP + j0) * 64;
        for (int i = tid; i < JT * 64; i += 256) {
            int row = i >> 6, ln = i & 63;
            uint u8 = src[(size_t)row * 64 + ln];
            f2v lo = __builtin_amdgcn_cvt_pk_f32_fp8((int)u8, false);
            f2v hi = __builtin_amdgcn_cvt_pk_f32_fp8((int)u8, true);
            uint2 pk;
            pk.x = bfb(lo.x) | ((uint)bfb(lo.y) << 16);
            pk.y = bfb(hi.x) | ((uint)bfb(hi.y) << 16);
            *(uint2*)&agg[row][ln * 4] = pk;
        }
    }
    __syncthreads();
    int lane = tid & 63;
    int w = __builtin_amdgcn_readfirstlane(tid >> 6);
    int col = lane & 15, rg = lane >> 4;
    s8v af[8];
#pragma unroll
    for (int kc = 0; kc < 8; ++kc)
        af[kc] = *(const s8v*)&agg[col][kc * 32 + rg * 8];
    float* outp = gaggP + ((size_t)b * 8 + blockIdx.x) * 256;
#pragma unroll
    for (int t = 0; t < 4; ++t) {
        int nt = w * 4 + t;
        f4v acc = (f4v){0.f, 0.f, 0.f, 0.f};
#pragma unroll
        for (int kc = 0; kc < 8; ++kc) {
            s8v bf = *(const s8v*)&w2f[(nt * 8 + kc) * 64 + lane];
            acc = __builtin_amdgcn_mfma_f32_16x16x32_bf16(af[kc], bf, acc, 0, 0, 0);
        }
        float bv = b2[nt * 16 + col];
        float p = 0.f;
#pragma unroll
        for (int i = 0; i < 4; ++i) {
            float vv = acc[i] + bv;
            vv = vv > 0.f ? vv : 0.f;
            p += vs[rg * 4 + i] * vv;
        }
        p += __shfl_xor(p, 16);
        p += __shfl_xor(p, 32);
        if (lane < 16) outp[nt * 16 + col] = p;
    }
}

// ---- k_gmm: ot<4: g = relu(sum(gaggP) @ w3 + b3) -> hbf[b][512+..] (bf16)
//      ot==4: hbf[b][0..511] = bf16(leaky(bn(hp0)))
__global__ __launch_bounds__(256) void k_gmm(const int* __restrict__ cnt,
                                             const int* __restrict__ sid_last,
                                             const float* __restrict__ gaggP,
                                             const float* __restrict__ w3,
                                             const float* __restrict__ b3,
                                             const float* __restrict__ hp0,
                                             const float* __restrict__ mu0,
                                             const float* __restrict__ rstd0,
                                             const float* __restrict__ gam,
                                             const float* __restrict__ bet,
                                             ushort* __restrict__ hbf) {
    int b = blockIdx.x, ot = blockIdx.y, tid = threadIdx.x;
    if (ot == 4) {
        for (int o = tid; o < 512; o += 256) {
            float v = hp0[b * 512 + o];
            v = gam[o] * (v - mu0[o]) * rstd0[o] + bet[o];
            v = v >= 0.f ? v : 0.01f * v;
            hbf[(size_t)b * 1024 + o] = bfb(v);
        }
        return;
    }
    __shared__ float h[256];
    {
        int m = sid_last[b];
        int cj = cnt[m];
        int nq = (cj + JT - 1) / JT;
        const float* p = gaggP + (size_t)b * 8 * 256 + tid;
        float s = 0.f;
        for (int q = 0; q < nq; ++q) s += p[q * 256];
        h[tid] = s;
    }
    __syncthreads();
    int q  = tid & 31;       // output quad
    int kg = tid >> 5;       // 0..7, K-group of 32
    const float4* w4 = (const float4*)w3;     // 128 quads per k-row
    int wq = ot * 32 + q;
    float4 acc = {0.f, 0.f, 0.f, 0.f};
    for (int k = kg * 32; k < kg * 32 + 32; ++k) {
        float hk = h[k];
        float4 w = w4[(size_t)k * 128 + wq];
        acc.x += hk * w.x; acc.y += hk * w.y; acc.z += hk * w.z; acc.w += hk * w.w;
    }
    __shared__ float4 red[8][32];
    red[kg][q] = acc;
    __syncthreads();
    if (tid < 32) {
        float4 s = red[0][tid];
#pragma unroll
        for (int gr = 1; gr < 8; ++gr) {
            float4 r = red[gr][tid];
            s.x += r.x; s.y += r.y; s.z += r.z; s.w += r.w;
        }
        int ob = ot * 128 + tid * 4;
        s.x += b3[ob];     s.x = s.x > 0.f ? s.x : 0.f;
        s.y += b3[ob + 1]; s.y = s.y > 0.f ? s.y : 0.f;
        s.z += b3[ob + 2]; s.z = s.z > 0.f ? s.z : 0.f;
        s.w += b3[ob + 3]; s.w = s.w > 0.f ? s.w : 0.f;
        uint2 pk;
        pk.x = bfb(s.x) | ((uint)bfb(s.y) << 16);
        pk.y = bfb(s.z) | ((uint)bfb(s.w) << 16);
        *(uint2*)&hbf[(size_t)b * 1024 + 512 + ob] = pk;
    }
}

// ---- k_fc1mm: hp1[128 x 512] = hbf[128 x 1024] @ wfc1 + b1 (MFMA) ---------
// grid 8 x 256: wave w -> col-tile ct_g = blk*4+w; acc[8] covers 128 rows
__global__ __launch_bounds__(256) void k_fc1mm(const ushort* __restrict__ hbf,
                                               const uint4* __restrict__ w3f,
                                               const float* __restrict__ b1,
                                               float* __restrict__ hp1) {
    int tid = threadIdx.x;
    int l = tid & 63;
    int w = __builtin_amdgcn_readfirstlane(tid >> 6);
    int ct_g = blockIdx.x * 4 + w;          // 0..31
    int lm = l & 15, lg = l >> 4;
    f4v acc[8];
#pragma unroll
    for (int rt = 0; rt < 8; ++rt) acc[rt] = (f4v){0.f, 0.f, 0.f, 0.f};
    for (int kc = 0; kc < 32; ++kc) {
        s8v bf = *(const s8v*)&w3f[(ct_g * 32 + kc) * 64 + l];
#pragma unroll
        for (int rt = 0; rt < 8; ++rt) {
            const ushort* ap = hbf + (size_t)(rt * 16 + lm) * 1024 + kc * 32 + lg * 8;
            s8v af = *(const s8v*)ap;
            acc[rt] = __builtin_amdgcn_mfma_f32_16x16x32_bf16(af, bf, acc[rt], 0, 0, 0);
        }
    }
    int n = ct_g * 16 + lm;
    float bv = b1[n];
#pragma unroll
    for (int rt = 0; rt < 8; ++rt) {
#pragma unroll
        for (int i = 0; i < 4; ++i) {
            int mrow = rt * 16 + lg * 4 + i;
            hp1[(size_t)mrow * 512 + n] = acc[rt][i] + bv;
        }
    }
}

// ---------------- k_bn1w: widened batch-norm stats for hp1 (grid 16) -------
__global__ __launch_bounds__(256) void k_bn1w(const float* __restrict__ h,
                                              float* __restrict__ mu,
                                              float* __restrict__ rstd) {
    int tid = threadIdx.x;
    int o = blockIdx.x * 32 + (tid & 31);
    int bg = tid >> 5;   // 0..7
    float s = 0.f, s2 = 0.f;
    for (int b = bg * 16; b < bg * 16 + 16; ++b) {
        float v = h[b * 512 + o];
        s += v; s2 += v * v;
    }
    __shared__ float rs[8][32], rs2[8][32];
    rs[bg][tid & 31] = s; rs2[bg][tid & 31] = s2;
    __syncthreads();
    if (tid < 32) {
        float S1 = 0.f, S2 = 0.f;
#pragma unroll
        for (int g2 = 0; g2 < 8; ++g2) { S1 += rs[g2][tid]; S2 += rs2[g2][tid]; }
        float m = S1 * (1.f / B);
        float var = S2 * (1.f / B) - m * m;
        mu[blockIdx.x * 32 + tid] = m;
        rstd[blockIdx.x * 32 + tid] = rsqrtf(var + 1e-5f);
    }
}

// ---------------- kernel 11: out = sigmoid(leaky(bn(hp1)) @ w2 + b2) -------
__global__ __launch_bounds__(64) void k_out(const float* __restrict__ hp1,
                                            const float* __restrict__ mu1,
                                            const float* __restrict__ rstd1,
                                            const float* __restrict__ gam,
                                            const float* __restrict__ bet,
                                            const float* __restrict__ w2,
                                            const float* __restrict__ b2,
                                            float* __restrict__ out) {
    int b = blockIdx.x, lane = threadIdx.x;
    float acc = 0.f;
    for (int o = lane; o < 512; o += 64) {
        float v = hp1[b * 512 + o];
        v = gam[o] * (v - mu1[o]) * rstd1[o] + bet[o];
        v = v >= 0.f ? v : 0.01f * v;
        acc += v * w2[o];
    }
    for (int off = 32; off > 0; off >>= 1) acc += __shfl_down(acc, off);
    if (lane == 0) out[b] = 1.f / (1.f + expf(-(acc + b2[0])));
}

static inline size_t align256(size_t x) { return (x + 255) & ~(size_t)255; }

extern "C" void kernel_launch(void* const* d_in, const int* in_sizes, int n_in,
                              void* d_out, int out_size, void* d_ws, size_t ws_size,
                              hipStream_t stream) {
    const float* x     = (const float*)d_in[0];
    const float* adj   = (const float*)d_in[1];
    const float* w_gc1 = (const float*)d_in[2];
    const float* b_gc1 = (const float*)d_in[3];
    const float* w_gc2 = (const float*)d_in[4];
    const float* b_gc2 = (const float*)d_in[5];
    const float* w_gc3 = (const float*)d_in[6];
    const float* b_gc3 = (const float*)d_in[7];
    const float* w_fc0 = (const float*)d_in[8];
    const float* b_fc0 = (const float*)d_in[9];
    const float* g_fc0 = (const float*)d_in[10];
    const float* be_fc0= (const float*)d_in[11];
    const float* w_fc1 = (const float*)d_in[12];
    const float* b_fc1 = (const float*)d_in[13];
    const float* g_fc1 = (const float*)d_in[14];
    const float* be_fc1= (const float*)d_in[15];
    const float* w_fc2 = (const float*)d_in[16];
    const float* b_fc2 = (const float*)d_in[17];

    char* wsp = (char*)d_ws;
    size_t off = 0;
    auto alloc = [&](size_t bytes) { void* p = wsp + off; off = align256(off + bytes); return p; };
    float* d_deg   = (float*)alloc((size_t)N * 4);
    int*   sid     = (int*)  alloc((size_t)B * 63 * 4);
    int*   sidl    = (int*)  alloc((size_t)B * 4);
    uint4* feA     = (uint4*)alloc((size_t)B * 2 * 64 * 16);
    uint4* wfrag   = (uint4*)alloc((size_t)1024 * 16);
    uint4* w2frag  = (uint4*)alloc((size_t)8192 * 16);
    uint4* w3frag  = (uint4*)alloc((size_t)65536 * 16);
    int*   csr_cnt = (int*)  alloc((size_t)N * 4);
    int*   csr_idx = (int*)  alloc((size_t)N * CAP * 4);
    float* csr_val = (float*)alloc((size_t)N * CAP * 4);
    unsigned char* X1   = (unsigned char*)alloc((size_t)B * N * 256);
    unsigned char* aggG = (unsigned char*)alloc((size_t)B * CAP * 256);
    float* gaggP   = (float*)alloc((size_t)B * 8 * 256 * 4);
    ushort* hbf    = (ushort*)alloc((size_t)B * 1024 * 2);
    float* hp0     = (float*)alloc((size_t)B * 512 * 4);
    float* mu0     = (float*)alloc(512 * 4);
    float* rstd0   = (float*)alloc(512 * 4);
    float* hp1     = (float*)alloc((size_t)B * 512 * 4);
    float* mu1     = (float*)alloc(512 * 4);
    float* rstd1   = (float*)alloc(512 * 4);

    k_prep0 <<<N + 36 + 256, 256, 0, stream>>>(adj, d_deg, w_gc1, w_gc2, w_fc1,
                                               wfrag, w2frag, w3frag);
    k_prep1 <<<500 + B + 256, 256, 0, stream>>>(adj, d_deg, x, csr_cnt, csr_idx, csr_val,
                                                sid, sidl, feA, w_fc0, b_fc0, hp0, mu0, rstd0);
    k_x1    <<<dim3(32, B), 256, 0, stream>>>(adj, d_deg, sid, feA, wfrag, b_gc1, X1);
    k_gather<<<dim3(CAP / JG, B), 256, 0, stream>>>(csr_cnt, csr_idx, csr_val, sidl, X1, aggG);
    k_x2g   <<<dim3(CAP / JT, B), 256, 0, stream>>>(csr_cnt, sidl, csr_val, aggG, w2frag, b_gc2, gaggP);
    k_gmm   <<<dim3(B, 5), 256, 0, stream>>>(csr_cnt, sidl, gaggP, w_gc3, b_gc3,
                                             hp0, mu0, rstd0, g_fc0, be_fc0, hbf);
    k_fc1mm <<<8, 256, 0, stream>>>(hbf, w3frag, b_fc1, hp1);
    k_bn1w  <<<16, 256, 0, stream>>>(hp1, mu1, rstd1);
    k_out   <<<B, 64, 0, stream>>>(hp1, mu1, rstd1, g_fc1, be_fc1, w_fc2, b_fc2, (float*)d_out);
}

// Round 19
// 118.919 us; speedup vs baseline: 1.1830x; 1.1830x over previous
//
#include <hip/hip_runtime.h>
#include <hip/hip_bf16.h>

typedef __hip_bfloat16 bf16;
typedef short s8v __attribute__((ext_vector_type(8)));
typedef float f4v __attribute__((ext_vector_type(4)));
typedef float f2v __attribute__((ext_vector_type(2)));

#define B   128
#define N   2000
#define S   64
#define CAP 128          // max neighbors per row (mean ~65, 8-sigma safe)
#define JT  16           // j-rows per block in k_x2g
#define JG  8            // j-rows per block in k_gather
#define XROW 1088        // S*17

__device__ inline ushort bfb(float v) {
    union { __hip_bfloat16 h; ushort u; } c; c.h = __float2bfloat16(v); return c.u;
}

// ---------------- k_prep0: rowsum (blk<N) + pack W frags (blk>=N) ----------
__global__ __launch_bounds__(256) void k_prep0(const float* __restrict__ adj,
                                               float* __restrict__ d,
                                               const float* __restrict__ w1,
                                               const float* __restrict__ w2,
                                               uint4* __restrict__ wf1,
                                               uint4* __restrict__ wf2) {
    int blk = blockIdx.x;
    if (blk < N) {
        int m = blk;
        const float* row = adj + (size_t)m * N;
        float s = 0.f;
        for (int c = threadIdx.x; c < N; c += 256) s += row[c];
        for (int o = 32; o > 0; o >>= 1) s += __shfl_down(s, o);
        __shared__ float red[4];
        int wave = threadIdx.x >> 6;
        if ((threadIdx.x & 63) == 0) red[wave] = s;
        __syncthreads();
        if (threadIdx.x == 0)
            d[m] = rsqrtf(red[0] + red[1] + red[2] + red[3] + 1.0f);
    } else {
        int blk2 = blk - N;
        if (blk2 < 4) {
            int e = blk2 * 256 + threadIdx.x;          // 0..1023
            int ct = e >> 6, l = e & 63;
            int kg = l >> 4, ch = ct * 16 + (l & 15);
            ushort h[8];
#pragma unroll
            for (int j = 0; j < 8; ++j) {
                int f = kg * 8 + j;
                h[j] = (f < 16) ? bfb(w1[f * 256 + ch]) : (ushort)0;
            }
            uint4 r;
            r.x = h[0] | ((uint)h[1] << 16);
            r.y = h[2] | ((uint)h[3] << 16);
            r.z = h[4] | ((uint)h[5] << 16);
            r.w = h[6] | ((uint)h[7] << 16);
            wf1[e] = r;
        } else {
            int e = (blk2 - 4) * 256 + threadIdx.x;    // 0..8191
            int l = e & 63;
            int kc = (e >> 6) & 7;
            int nt = e >> 9;
            int col = l & 15, kg = l >> 4;
            ushort h[8];
#pragma unroll
            for (int i = 0; i < 8; ++i) {
                int k = kc * 32 + kg * 8 + i;
                h[i] = bfb(w2[k * 256 + nt * 16 + col]);
            }
            uint4 r;
            r.x = h[0] | ((uint)h[1] << 16);
            r.y = h[2] | ((uint)h[3] << 16);
            r.z = h[4] | ((uint)h[5] << 16);
            r.w = h[6] | ((uint)h[7] << 16);
            wf2[e] = r;
        }
    }
}

// ---- k_prep1: CSR x4/block (blk<500) + extract (500..627) + fc0s (>=628) --
__global__ __launch_bounds__(256) void k_prep1(const float* __restrict__ adj,
                                               const float* __restrict__ d,
                                               const float* __restrict__ x,
                                               int* __restrict__ cnt,
                                               int* __restrict__ idx,
                                               float* __restrict__ val,
                                               int* __restrict__ sid,
                                               int* __restrict__ sid_last,
                                               uint4* __restrict__ feA,
                                               const float* __restrict__ w0,
                                               const float* __restrict__ b0,
                                               float* __restrict__ hp0,
                                               float* __restrict__ mu0,
                                               float* __restrict__ rstd0) {
    int blk = blockIdx.x;
    if (blk < 500) {
        int m = blk * 4 + (threadIdx.x >> 6);
        int lane = threadIdx.x & 63;
        const float* row = adj + (size_t)m * N;
        float dm = d[m];
        int base = 0;
        for (int c0 = 0; c0 < N; c0 += 64) {
            int c = c0 + lane;
            float a = 0.f;
            if (c < N) { a = row[c]; if (c == m) a += 1.0f; }
            bool pred = (a != 0.f);
            unsigned long long mask = __ballot(pred);
            int pos = base + __popcll(mask & ((1ull << lane) - 1ull));
            if (pred && pos < CAP) {
                idx[m * CAP + pos] = c;
                val[m * CAP + pos] = dm * d[c] * a;
            }
            base += (int)__popcll(mask);
        }
        if (lane == 0) cnt[m] = base < CAP ? base : CAP;
    } else if (blk < 500 + B) {
        int b = blk - 500, tid = threadIdx.x;
        const float* xb = x + (size_t)b * XROW;
        __shared__ float dss_sh[63];
        __shared__ float fe_sh[64][16];
        if (tid < S - 1) {
            int s_ = (int)xb[tid * 17 + 15];
            sid[b * (S - 1) + tid] = s_;
            dss_sh[tid] = d[s_];
        }
        if (tid == S - 1) sid_last[b] = (int)xb[(S - 1) * 17 + 15];
        if (tid >= 240 && tid < 256) fe_sh[63][tid - 240] = 0.f;   // zero pad
        __syncthreads();
        for (int i = tid; i < (S - 1) * 16; i += 256) {
            int t = i >> 4, f = i & 15;
            fe_sh[t][f] = dss_sh[t] * xb[t * 17 + (f < 15 ? f : 16)];
        }
        __syncthreads();
        if (tid < 128) {
            int kc = tid >> 6, l = tid & 63;
            int f = l & 15, tg = l >> 4;
            ushort h[8];
#pragma unroll
            for (int j = 0; j < 8; ++j)
                h[j] = bfb(fe_sh[kc * 32 + tg * 8 + j][f]);
            uint4 r;
            r.x = h[0] | ((uint)h[1] << 16);
            r.y = h[2] | ((uint)h[3] << 16);
            r.z = h[4] | ((uint)h[5] << 16);
            r.w = h[6] | ((uint)h[7] << 16);
            feA[(b * 2 + kc) * 64 + l] = r;
        }
    } else {
        // fused fc0 + batch stats: block = 2 channels x 128 batch
        int tid = threadIdx.x;
        int c = tid >> 7, b = tid & 127;
        int o = (blk - 500 - B) * 2 + c;
        const float* xr = x + (size_t)b * XROW + (S - 1) * 17;
        float acc = b0[o];
#pragma unroll
        for (int f = 0; f < 15; ++f) acc += xr[f] * w0[f * 512 + o];
        hp0[b * 512 + o] = acc;
        float s = acc, s2 = acc * acc;
        for (int off = 32; off > 0; off >>= 1) {
            s += __shfl_down(s, off);
            s2 += __shfl_down(s2, off);
        }
        __shared__ float rs[4], rs2[4];
        int wv = tid >> 6;
        if ((tid & 63) == 0) { rs[wv] = s; rs2[wv] = s2; }
        __syncthreads();
        if ((tid & 127) == 0) {
            float S1 = rs[c * 2] + rs[c * 2 + 1];
            float S2 = rs2[c * 2] + rs2[c * 2 + 1];
            float m = S1 * (1.f / B);
            float var = S2 * (1.f / B) - m * m;
            mu0[o] = m;
            rstd0[o] = rsqrtf(var + 1e-5f);
        }
    }
}

// ---------------- kernel 4: X1[b,p,:] = relu((Ahat X)[b,p] @ w1 + b1) ------
// fp8 X1; LDS-bounce transpose (Xs UNION'd over Ylds: 23.8 -> 18.7 KB LDS)
__global__ __launch_bounds__(256) void k_x1(const float* __restrict__ adj,
                                            const float* __restrict__ d,
                                            const int* __restrict__ sid,
                                            const uint4* __restrict__ feA,
                                            const uint4* __restrict__ wfrag,
                                            const float* __restrict__ b1,
                                            unsigned char* __restrict__ X1) {
    __shared__ int sv[64];
    __shared__ float b1s[256];
    __shared__ __align__(16) union SU {
        ushort Ylds[64][40];     // 80B rows (phase 1 -> phase 2 hand-off)
        uint   Xs[4][16][68];    // epilogue transpose tile (after Ylds dead)
    } su;
    int b = blockIdx.y, p0 = blockIdx.x * 64, tid = threadIdx.x;
    b1s[tid] = b1[tid];
    if (tid < 63) sv[tid] = sid[b * 63 + tid];
    if (tid == 63) sv[63] = 0;
    __syncthreads();

    int l = tid & 63, wv = tid >> 6;
    int lm = l & 15, lg = l >> 4;
    int pt = p0 + wv * 16;
    int pcol = pt + lm;
    bool pv = (pcol < N);
    int pc = pv ? pcol : 0;

    s8v a1_0 = *(const s8v*)&feA[(b * 2 + 0) * 64 + l];
    s8v a1_1 = *(const s8v*)&feA[(b * 2 + 1) * 64 + l];

    int ss[16];
#pragma unroll
    for (int q = 0; q < 16; ++q)
        ss[q] = sv[(q >> 3) * 32 + lg * 8 + (q & 7)];
    float av[16];
#pragma unroll
    for (int q = 0; q < 16; ++q)
        av[q] = adj[(size_t)ss[q] * N + pc];
#pragma unroll
    for (int q = 0; q < 16; ++q) {
        av[q] = pv ? av[q] : 0.f;
        if (pcol == ss[q]) av[q] += 1.0f;
    }
    ushort h[16];
#pragma unroll
    for (int q = 0; q < 16; ++q) h[q] = bfb(av[q]);
    s8v b1f, b2f;
    {
        uint4 t0, t1;
        t0.x = h[0] | ((uint)h[1] << 16);  t0.y = h[2] | ((uint)h[3] << 16);
        t0.z = h[4] | ((uint)h[5] << 16);  t0.w = h[6] | ((uint)h[7] << 16);
        t1.x = h[8] | ((uint)h[9] << 16);  t1.y = h[10] | ((uint)h[11] << 16);
        t1.z = h[12] | ((uint)h[13] << 16); t1.w = h[14] | ((uint)h[15] << 16);
        b1f = *(s8v*)&t0; b2f = *(s8v*)&t1;
    }
    f4v D1 = (f4v){0.f, 0.f, 0.f, 0.f};
    D1 = __builtin_amdgcn_mfma_f32_16x16x32_bf16(a1_0, b1f, D1, 0, 0, 0);
    D1 = __builtin_amdgcn_mfma_f32_16x16x32_bf16(a1_1, b2f, D1, 0, 0, 0);
    float dp = d[pc] * (pv ? 1.f : 0.f);
    uint2 pk;
    pk.x = bfb(D1[0] * dp) | ((uint)bfb(D1[1] * dp) << 16);
    pk.y = bfb(D1[2] * dp) | ((uint)bfb(D1[3] * dp) << 16);
    *(uint2*)&su.Ylds[wv * 16 + lm][lg * 4] = pk;
    *(uint2*)&su.Ylds[wv * 16 + lm][16 + lg * 4] = make_uint2(0u, 0u);  // K-pad
    __syncthreads();

    s8v yf = *(const s8v*)&su.Ylds[wv * 16 + lm][lg * 8];   // B = Y^T frag
    __syncthreads();   // all yf read before Xs overwrites Ylds (union)
    f4v acc2[16];
#pragma unroll
    for (int ct = 0; ct < 16; ++ct) acc2[ct] = (f4v){0.f, 0.f, 0.f, 0.f};
#pragma unroll
    for (int ct = 0; ct < 16; ++ct) {
        s8v wfv = *(const s8v*)&wfrag[ct * 64 + l];         // A = W^T frag
        acc2[ct] = __builtin_amdgcn_mfma_f32_16x16x32_bf16(wfv, yf, acc2[ct], 0, 0, 0);
    }
    // epilogue: bias+relu+fp8-pack into per-wave LDS tile (transpose)
#pragma unroll
    for (int ct = 0; ct < 16; ++ct) {
        float4 bz = *(float4*)&b1s[ct * 16 + lg * 4];
        float v0 = acc2[ct][0] + bz.x; v0 = v0 > 0.f ? v0 : 0.f;
        float v1 = acc2[ct][1] + bz.y; v1 = v1 > 0.f ? v1 : 0.f;
        float v2 = acc2[ct][2] + bz.z; v2 = v2 > 0.f ? v2 : 0.f;
        float v3 = acc2[ct][3] + bz.w; v3 = v3 > 0.f ? v3 : 0.f;
        uint pk8 = (uint)__builtin_amdgcn_cvt_pk_fp8_f32(v0, v1, 0, false);
        pk8 = (uint)__builtin_amdgcn_cvt_pk_fp8_f32(v2, v3, (int)pk8, true);
        su.Xs[wv][lm][ct * 4 + lg] = pk8;
    }
    __syncthreads();
    {
        uint4* dstb = (uint4*)((uint*)X1 + ((size_t)b * N + p0 + wv * 16) * 64);
#pragma unroll
        for (int i = 0; i < 4; ++i) {
            int g = l + 64 * i;
            int r = g >> 4, c4 = g & 15;
            if (p0 + wv * 16 + r < N)
                dstb[g] = *(uint4*)&su.Xs[wv][r][c4 * 4];
        }
    }
}

// ---------------- kernel 5a: k_gather — fp8 agg out, 4-deep prefetch -------
__global__ __launch_bounds__(256) void k_gather(const int* __restrict__ cnt,
                                                const int* __restrict__ idxA,
                                                const float* __restrict__ valA,
                                                const int* __restrict__ sid_last,
                                                const unsigned char* __restrict__ X1,
                                                unsigned char* __restrict__ aggG) {
    __shared__ int   nns[JG];
    __shared__ int   ncn_s[JG];
    __shared__ int   nidx[JG][CAP];
    __shared__ float nval[JG][CAP];
    int b = blockIdx.y, j0 = blockIdx.x * JG, tid = threadIdx.x;
    int m = sid_last[b];
    int cj = cnt[m];
    if (tid < JG) {
        int j = j0 + tid;
        int n = idxA[m * CAP + (j < cj ? j : 0)];
        nns[tid] = n;
        ncn_s[tid] = (j < cj) ? cnt[n] : 0;
    }
    __syncthreads();
    for (int i = tid; i < JG * CAP; i += 256) {
        int jj = i >> 7, k = i & (CAP - 1);
        int n = nns[jj], c = ncn_s[jj];
        nidx[jj][k] = (k < c) ? idxA[n * CAP + k] : 0;
        nval[jj][k] = (k < c) ? valA[n * CAP + k] : 0.f;
    }
    __syncthreads();
    int lane = tid & 63;
    int w = __builtin_amdgcn_readfirstlane(tid >> 6);
    int la = w * 2, lb = la + 1;
    const uint* X1bl = (const uint*)X1 + (size_t)b * N * 64 + lane;
    int cA = ncn_s[la], cB = ncn_s[lb];
    int cmax = cA > cB ? cA : cB;
    float aA0 = 0.f, aA1 = 0.f, aA2 = 0.f, aA3 = 0.f;
    float aB0 = 0.f, aB1 = 0.f, aB2 = 0.f, aB3 = 0.f;
    if (cmax > 0) {
        uint uA0, uA1, uA2, uA3, uB0, uB1, uB2, uB3;
        float vA0, vA1, vA2, vA3, vB0, vB1, vB2, vB3;
        uA0 = X1bl[(size_t)nidx[la][0] * 64]; vA0 = nval[la][0];
        uA1 = X1bl[(size_t)nidx[la][1] * 64]; vA1 = nval[la][1];
        uA2 = X1bl[(size_t)nidx[la][2] * 64]; vA2 = nval[la][2];
        uA3 = X1bl[(size_t)nidx[la][3] * 64]; vA3 = nval[la][3];
        uB0 = X1bl[(size_t)nidx[lb][0] * 64]; vB0 = nval[lb][0];
        uB1 = X1bl[(size_t)nidx[lb][1] * 64]; vB1 = nval[lb][1];
        uB2 = X1bl[(size_t)nidx[lb][2] * 64]; vB2 = nval[lb][2];
        uB3 = X1bl[(size_t)nidx[lb][3] * 64]; vB3 = nval[lb][3];
        int c4 = (cmax + 3) & ~3;
        for (int k = 0; k < c4; k += 4) {
            uint cA0 = uA0, cA1 = uA1, cA2 = uA2, cA3 = uA3;
            uint cB0 = uB0, cB1 = uB1, cB2 = uB2, cB3 = uB3;
            float wA0 = vA0, wA1 = vA1, wA2 = vA2, wA3 = vA3;
            float wB0 = vB0, wB1 = vB1, wB2 = vB2, wB3 = vB3;
            int k4 = k + 4; k4 = k4 < CAP ? k4 : CAP - 1;
            int k5 = k + 5; k5 = k5 < CAP ? k5 : CAP - 1;
            int k6 = k + 6; k6 = k6 < CAP ? k6 : CAP - 1;
            int k7 = k + 7; k7 = k7 < CAP ? k7 : CAP - 1;
            uA0 = X1bl[(size_t)nidx[la][k4] * 64]; vA0 = nval[la][k4];
            uA1 = X1bl[(size_t)nidx[la][k5] * 64]; vA1 = nval[la][k5];
            uA2 = X1bl[(size_t)nidx[la][k6] * 64]; vA2 = nval[la][k6];
            uA3 = X1bl[(size_t)nidx[la][k7] * 64]; vA3 = nval[la][k7];
            uB0 = X1bl[(size_t)nidx[lb][k4] * 64]; vB0 = nval[lb][k4];
            uB1 = X1bl[(size_t)nidx[lb][k5] * 64]; vB1 = nval[lb][k5];
            uB2 = X1bl[(size_t)nidx[lb][k6] * 64]; vB2 = nval[lb][k6];
            uB3 = X1bl[(size_t)nidx[lb][k7] * 64]; vB3 = nval[lb][k7];
            f2v lo, hi;
            lo = __builtin_amdgcn_cvt_pk_f32_fp8((int)cA0, false);
            hi = __builtin_amdgcn_cvt_pk_f32_fp8((int)cA0, true);
            aA0 += wA0 * lo.x; aA1 += wA0 * lo.y; aA2 += wA0 * hi.x; aA3 += wA0 * hi.y;
            lo = __builtin_amdgcn_cvt_pk_f32_fp8((int)cA1, false);
            hi = __builtin_amdgcn_cvt_pk_f32_fp8((int)cA1, true);
            aA0 += wA1 * lo.x; aA1 += wA1 * lo.y; aA2 += wA1 * hi.x; aA3 += wA1 * hi.y;
            lo = __builtin_amdgcn_cvt_pk_f32_fp8((int)cA2, false);
            hi = __builtin_amdgcn_cvt_pk_f32_fp8((int)cA2, true);
            aA0 += wA2 * lo.x; aA1 += wA2 * lo.y; aA2 += wA2 * hi.x; aA3 += wA2 * hi.y;
            lo = __builtin_amdgcn_cvt_pk_f32_fp8((int)cA3, false);
            hi = __builtin_amdgcn_cvt_pk_f32_fp8((int)cA3, true);
            aA0 += wA3 * lo.x; aA1 += wA3 * lo.y; aA2 += wA3 * hi.x; aA3 += wA3 * hi.y;
            lo = __builtin_amdgcn_cvt_pk_f32_fp8((int)cB0, false);
            hi = __builtin_amdgcn_cvt_pk_f32_fp8((int)cB0, true);
            aB0 += wB0 * lo.x; aB1 += wB0 * lo.y; aB2 += wB0 * hi.x; aB3 += wB0 * hi.y;
            lo = __builtin_amdgcn_cvt_pk_f32_fp8((int)cB1, false);
            hi = __builtin_amdgcn_cvt_pk_f32_fp8((int)cB1, true);
            aB0 += wB1 * lo.x; aB1 += wB1 * lo.y; aB2 += wB1 * hi.x; aB3 += wB1 * hi.y;
            lo = __builtin_amdgcn_cvt_pk_f32_fp8((int)cB2, false);
            hi = __builtin_amdgcn_cvt_pk_f32_fp8((int)cB2, true);
            aB0 += wB2 * lo.x; aB1 += wB2 * lo.y; aB2 += wB2 * hi.x; aB3 += wB2 * hi.y;
            lo = __builtin_amdgcn_cvt_pk_f32_fp8((int)cB3, false);
            hi = __builtin_amdgcn_cvt_pk_f32_fp8((int)cB3, true);
            aB0 += wB3 * lo.x; aB1 += wB3 * lo.y; aB2 += wB3 * hi.x; aB3 += wB3 * hi.y;
        }
    }
    uint pkA = (uint)__builtin_amdgcn_cvt_pk_fp8_f32(aA0, aA1, 0, false);
    pkA = (uint)__builtin_amdgcn_cvt_pk_fp8_f32(aA2, aA3, (int)pkA, true);
    uint pkB = (uint)__builtin_amdgcn_cvt_pk_fp8_f32(aB0, aB1, 0, false);
    pkB = (uint)__builtin_amdgcn_cvt_pk_fp8_f32(aB2, aB3, (int)pkB, true);
    uint* ag = (uint*)aggG;
    ag[((size_t)b * CAP + j0 + la) * 64 + lane] = pkA;
    ag[((size_t)b * CAP + j0 + lb) * 64 + lane] = pkB;
}

// ---------------- kernel 5b: k_x2g — fp8 agg in, MFMA + j-reduction --------
__global__ __launch_bounds__(256) void k_x2g(const int* __restrict__ cnt,
                                             const int* __restrict__ sid_last,
                                             const float* __restrict__ valA,
                                             const unsigned char* __restrict__ aggG,
                                             const uint4* __restrict__ w2f,
                                             const float* __restrict__ b2,
                                             float* __restrict__ gaggP) {
    __shared__ ushort agg[JT][264];   // 528B row stride (bf16, unpacked)
    __shared__ float vs[JT];
    int b = blockIdx.y, j0 = blockIdx.x * JT, tid = threadIdx.x;
    int m = sid_last[b];
    int cj = cnt[m];
    if (j0 >= cj) return;
    int nj = cj - j0; if (nj > JT) nj = JT;
    if (tid < JT) vs[tid] = (tid < nj) ? valA[m * CAP + j0 + tid] : 0.f;
    {
        const uint* src = (const uint*)aggG + ((size_t)b * CAP + j0) * 64;
        for (int i = tid; i < JT * 64; i += 256) {
            int row = i >> 6, ln = i & 63;
            uint u8 = src[(size_t)row * 64 + ln];
            f2v lo = __builtin_amdgcn_cvt_pk_f32_fp8((int)u8, false);
            f2v hi = __builtin_amdgcn_cvt_pk_f32_fp8((int)u8, true);
            uint2 pk;
            pk.x = bfb(lo.x) | ((uint)bfb(lo.y) << 16);
            pk.y = bfb(hi.x) | ((uint)bfb(hi.y) << 16);
            *(uint2*)&agg[row][ln * 4] = pk;
        }
    }
    __syncthreads();
    int lane = tid & 63;
    int w = __builtin_amdgcn_readfirstlane(tid >> 6);
    int col = lane & 15, rg = lane >> 4;
    s8v af[8];
#pragma unroll
    for (int kc = 0; kc < 8; ++kc)
        af[kc] = *(const s8v*)&agg[col][kc * 32 + rg * 8];
    float* outp = gaggP + ((size_t)b * 8 + blockIdx.x) * 256;
#pragma unroll
    for (int t = 0; t < 4; ++t) {
        int nt = w * 4 + t;
        f4v acc = (f4v){0.f, 0.f, 0.f, 0.f};
#pragma unroll
        for (int kc = 0; kc < 8; ++kc) {
            s8v bf = *(const s8v*)&w2f[(nt * 8 + kc) * 64 + lane];
            acc = __builtin_amdgcn_mfma_f32_16x16x32_bf16(af[kc], bf, acc, 0, 0, 0);
        }
        float bv = b2[nt * 16 + col];
        float p = 0.f;
#pragma unroll
        for (int i = 0; i < 4; ++i) {
            float vv = acc[i] + bv;
            vv = vv > 0.f ? vv : 0.f;
            p += vs[rg * 4 + i] * vv;
        }
        p += __shfl_xor(p, 16);
        p += __shfl_xor(p, 32);
        if (lane < 16) outp[nt * 16 + col] = p;
    }
}

// ---------------- k_gmm — g = relu(sum(gaggP) @ w3 + b3) -------------------
__global__ __launch_bounds__(256) void k_gmm(const int* __restrict__ cnt,
                                             const int* __restrict__ sid_last,
                                             const float* __restrict__ gaggP,
                                             const float* __restrict__ w3,
                                             const float* __restrict__ b3,
                                             float* __restrict__ g) {
    int b = blockIdx.x, ot = blockIdx.y, tid = threadIdx.x;
    __shared__ float h[256];
    {
        int m = sid_last[b];
        int cj = cnt[m];
        int nq = (cj + JT - 1) / JT;
        const float* p = gaggP + (size_t)b * 8 * 256 + tid;
        float s = 0.f;
        for (int q = 0; q < nq; ++q) s += p[q * 256];
        h[tid] = s;
    }
    __syncthreads();
    int q  = tid & 31;       // output quad
    int kg = tid >> 5;       // 0..7, K-group of 32
    const float4* w4 = (const float4*)w3;     // 128 quads per k-row
    int wq = ot * 32 + q;
    float4 acc = {0.f, 0.f, 0.f, 0.f};
    for (int k = kg * 32; k < kg * 32 + 32; ++k) {
        float hk = h[k];
        float4 w = w4[(size_t)k * 128 + wq];
        acc.x += hk * w.x; acc.y += hk * w.y; acc.z += hk * w.z; acc.w += hk * w.w;
    }
    __shared__ float4 red[8][32];
    red[kg][q] = acc;
    __syncthreads();
    if (tid < 32) {
        float4 s = red[0][tid];
#pragma unroll
        for (int gr = 1; gr < 8; ++gr) {
            float4 r = red[gr][tid];
            s.x += r.x; s.y += r.y; s.z += r.z; s.w += r.w;
        }
        int ob = ot * 128 + tid * 4;
        s.x += b3[ob];     s.x = s.x > 0.f ? s.x : 0.f;
        s.y += b3[ob + 1]; s.y = s.y > 0.f ? s.y : 0.f;
        s.z += b3[ob + 2]; s.z = s.z > 0.f ? s.z : 0.f;
        s.w += b3[ob + 3]; s.w = s.w > 0.f ? s.w : 0.f;
        *(float4*)&g[(size_t)b * 512 + ob] = s;
    }
}

// ---------------- k_bn1w: widened batch-norm stats for hp1 (grid 16) -------
__global__ __launch_bounds__(256) void k_bn1w(const float* __restrict__ h,
                                              float* __restrict__ mu,
                                              float* __restrict__ rstd) {
    int tid = threadIdx.x;
    int o = blockIdx.x * 32 + (tid & 31);
    int bg = tid >> 5;   // 0..7
    float s = 0.f, s2 = 0.f;
    for (int b = bg * 16; b < bg * 16 + 16; ++b) {
        float v = h[b * 512 + o];
        s += v; s2 += v * v;
    }
    __shared__ float rs[8][32], rs2[8][32];
    rs[bg][tid & 31] = s; rs2[bg][tid & 31] = s2;
    __syncthreads();
    if (tid < 32) {
        float S1 = 0.f, S2 = 0.f;
#pragma unroll
        for (int g2 = 0; g2 < 8; ++g2) { S1 += rs[g2][tid]; S2 += rs2[g2][tid]; }
        float m = S1 * (1.f / B);
        float var = S2 * (1.f / B) - m * m;
        mu[blockIdx.x * 32 + tid] = m;
        rstd[blockIdx.x * 32 + tid] = rsqrtf(var + 1e-5f);
    }
}

// ---------------- kernel 9: hp1 = [leaky(bn(hp0)), g] @ w1 + b1 ------------
__global__ __launch_bounds__(256) void k_fc1(const float* __restrict__ hp0,
                                             const float* __restrict__ mu0,
                                             const float* __restrict__ rstd0,
                                             const float* __restrict__ gam,
                                             const float* __restrict__ bet,
                                             const float* __restrict__ gbuf,
                                             const float* __restrict__ w1,
                                             const float* __restrict__ b1,
                                             float* __restrict__ hp1) {
    int b = blockIdx.x, ot = blockIdx.y, tid = threadIdx.x;
    __shared__ float h[1024];
    for (int o = tid; o < 512; o += 256) {
        float v = hp0[b * 512 + o];
        v = gam[o] * (v - mu0[o]) * rstd0[o] + bet[o];
        h[o] = v >= 0.f ? v : 0.01f * v;
        h[512 + o] = gbuf[(size_t)b * 512 + o];
    }
    __syncthreads();
    int q  = tid & 31;
    int kg = tid >> 5;
    const float4* w4 = (const float4*)w1;
    int wq = ot * 32 + q;
    float4 acc = {0.f, 0.f, 0.f, 0.f};
    for (int k = kg * 128; k < kg * 128 + 128; ++k) {
        float hk = h[k];
        float4 w = w4[(size_t)k * 128 + wq];
        acc.x += hk * w.x; acc.y += hk * w.y; acc.z += hk * w.z; acc.w += hk * w.w;
    }
    __shared__ float4 red[8][32];
    red[kg][q] = acc;
    __syncthreads();
    if (tid < 32) {
        float4 s = red[0][tid];
#pragma unroll
        for (int gr = 1; gr < 8; ++gr) {
            float4 r = red[gr][tid];
            s.x += r.x; s.y += r.y; s.z += r.z; s.w += r.w;
        }
        int ob = ot * 128 + tid * 4;
        s.x += b1[ob]; s.y += b1[ob + 1]; s.z += b1[ob + 2]; s.w += b1[ob + 3];
        *(float4*)&hp1[b * 512 + ob] = s;
    }
}

// ---------------- kernel 11: out = sigmoid(leaky(bn(hp1)) @ w2 + b2) -------
__global__ __launch_bounds__(64) void k_out(const float* __restrict__ hp1,
                                            const float* __restrict__ mu1,
                                            const float* __restrict__ rstd1,
                                            const float* __restrict__ gam,
                                            const float* __restrict__ bet,
                                            const float* __restrict__ w2,
                                            const float* __restrict__ b2,
                                            float* __restrict__ out) {
    int b = blockIdx.x, lane = threadIdx.x;
    float acc = 0.f;
    for (int o = lane; o < 512; o += 64) {
        float v = hp1[b * 512 + o];
        v = gam[o] * (v - mu1[o]) * rstd1[o] + bet[o];
        v = v >= 0.f ? v : 0.01f * v;
        acc += v * w2[o];
    }
    for (int off = 32; off > 0; off >>= 1) acc += __shfl_down(acc, off);
    if (lane == 0) out[b] = 1.f / (1.f + expf(-(acc + b2[0])));
}

static inline size_t align256(size_t x) { return (x + 255) & ~(size_t)255; }

extern "C" void kernel_launch(void* const* d_in, const int* in_sizes, int n_in,
                              void* d_out, int out_size, void* d_ws, size_t ws_size,
                              hipStream_t stream) {
    const float* x     = (const float*)d_in[0];
    const float* adj   = (const float*)d_in[1];
    const float* w_gc1 = (const float*)d_in[2];
    const float* b_gc1 = (const float*)d_in[3];
    const float* w_gc2 = (const float*)d_in[4];
    const float* b_gc2 = (const float*)d_in[5];
    const float* w_gc3 = (const float*)d_in[6];
    const float* b_gc3 = (const float*)d_in[7];
    const float* w_fc0 = (const float*)d_in[8];
    const float* b_fc0 = (const float*)d_in[9];
    const float* g_fc0 = (const float*)d_in[10];
    const float* be_fc0= (const float*)d_in[11];
    const float* w_fc1 = (const float*)d_in[12];
    const float* b_fc1 = (const float*)d_in[13];
    const float* g_fc1 = (const float*)d_in[14];
    const float* be_fc1= (const float*)d_in[15];
    const float* w_fc2 = (const float*)d_in[16];
    const float* b_fc2 = (const float*)d_in[17];

    char* wsp = (char*)d_ws;
    size_t off = 0;
    auto alloc = [&](size_t bytes) { void* p = wsp + off; off = align256(off + bytes); return p; };
    float* d_deg   = (float*)alloc((size_t)N * 4);
    int*   sid     = (int*)  alloc((size_t)B * 63 * 4);
    int*   sidl    = (int*)  alloc((size_t)B * 4);
    uint4* feA     = (uint4*)alloc((size_t)B * 2 * 64 * 16);
    uint4* wfrag   = (uint4*)alloc((size_t)1024 * 16);
    uint4* w2frag  = (uint4*)alloc((size_t)8192 * 16);
    int*   csr_cnt = (int*)  alloc((size_t)N * 4);
    int*   csr_idx = (int*)  alloc((size_t)N * CAP * 4);
    float* csr_val = (float*)alloc((size_t)N * CAP * 4);
    unsigned char* X1   = (unsigned char*)alloc((size_t)B * N * 256);
    unsigned char* aggG = (unsigned char*)alloc((size_t)B * CAP * 256);
    float* gaggP   = (float*)alloc((size_t)B * 8 * 256 * 4);
    float* gbuf    = (float*)alloc((size_t)B * 512 * 4);
    float* hp0     = (float*)alloc((size_t)B * 512 * 4);
    float* mu0     = (float*)alloc(512 * 4);
    float* rstd0   = (float*)alloc(512 * 4);
    float* hp1     = (float*)alloc((size_t)B * 512 * 4);
    float* mu1     = (float*)alloc(512 * 4);
    float* rstd1   = (float*)alloc(512 * 4);

    k_prep0 <<<N + 36, 256, 0, stream>>>(adj, d_deg, w_gc1, w_gc2, wfrag, w2frag);
    k_prep1 <<<500 + B + 256, 256, 0, stream>>>(adj, d_deg, x, csr_cnt, csr_idx, csr_val,
                                                sid, sidl, feA, w_fc0, b_fc0, hp0, mu0, rstd0);
    k_x1    <<<dim3(32, B), 256, 0, stream>>>(adj, d_deg, sid, feA, wfrag, b_gc1, X1);
    k_gather<<<dim3(CAP / JG, B), 256, 0, stream>>>(csr_cnt, csr_idx, csr_val, sidl, X1, aggG);
    k_x2g   <<<dim3(CAP / JT, B), 256, 0, stream>>>(csr_cnt, sidl, csr_val, aggG, w2frag, b_gc2, gaggP);
    k_gmm   <<<dim3(B, 4), 256, 0, stream>>>(csr_cnt, sidl, gaggP, w_gc3, b_gc3, gbuf);
    k_fc1   <<<dim3(B, 4), 256, 0, stream>>>(hp0, mu0, rstd0, g_fc0, be_fc0, gbuf, w_fc1, b_fc1, hp1);
    k_bn1w  <<<16, 256, 0, stream>>>(hp1, mu1, rstd1);
    k_out   <<<B, 64, 0, stream>>>(hp1, mu1, rstd1, g_fc1, be_fc1, w_fc2, b_fc2, (float*)d_out);
}

// Round 20
// 116.513 us; speedup vs baseline: 1.2074x; 1.0206x over previous
//
#include <hip/hip_runtime.h>
#include <hip/hip_bf16.h>

typedef __hip_bfloat16 bf16;
typedef short s8v __attribute__((ext_vector_type(8)));
typedef float f4v __attribute__((ext_vector_type(4)));
typedef float f2v __attribute__((ext_vector_type(2)));

#define B   128
#define N   2000
#define S   64
#define CAP 128          // max neighbors per row (mean ~65, 8-sigma safe)
#define JT  16           // j-rows per block in k_x2g
#define JG  8            // j-rows per block in k_gather
#define XROW 1088        // S*17

__device__ inline ushort bfb(float v) {
    union { __hip_bfloat16 h; ushort u; } c; c.h = __float2bfloat16(v); return c.u;
}

// ---- k_prep0: rowsum + adj8 conversion (blk<N) + pack W frags (blk>=N) ----
__global__ __launch_bounds__(256) void k_prep0(const float* __restrict__ adj,
                                               float* __restrict__ d,
                                               unsigned char* __restrict__ adj8,
                                               const float* __restrict__ w1,
                                               const float* __restrict__ w2,
                                               uint4* __restrict__ wf1,
                                               uint4* __restrict__ wf2) {
    int blk = blockIdx.x;
    if (blk < N) {
        int m = blk;
        const float* row = adj + (size_t)m * N;
        unsigned char* row8 = adj8 + (size_t)m * N;
        float s = 0.f;
        for (int c = threadIdx.x; c < N; c += 256) {
            float a = row[c];
            s += a;
            row8[c] = (unsigned char)(a != 0.f ? 1 : 0);
        }
        for (int o = 32; o > 0; o >>= 1) s += __shfl_down(s, o);
        __shared__ float red[4];
        int wave = threadIdx.x >> 6;
        if ((threadIdx.x & 63) == 0) red[wave] = s;
        __syncthreads();
        if (threadIdx.x == 0)
            d[m] = rsqrtf(red[0] + red[1] + red[2] + red[3] + 1.0f);
    } else {
        int blk2 = blk - N;
        if (blk2 < 4) {
            int e = blk2 * 256 + threadIdx.x;          // 0..1023
            int ct = e >> 6, l = e & 63;
            int kg = l >> 4, ch = ct * 16 + (l & 15);
            ushort h[8];
#pragma unroll
            for (int j = 0; j < 8; ++j) {
                int f = kg * 8 + j;
                h[j] = (f < 16) ? bfb(w1[f * 256 + ch]) : (ushort)0;
            }
            uint4 r;
            r.x = h[0] | ((uint)h[1] << 16);
            r.y = h[2] | ((uint)h[3] << 16);
            r.z = h[4] | ((uint)h[5] << 16);
            r.w = h[6] | ((uint)h[7] << 16);
            wf1[e] = r;
        } else {
            int e = (blk2 - 4) * 256 + threadIdx.x;    // 0..8191
            int l = e & 63;
            int kc = (e >> 6) & 7;
            int nt = e >> 9;
            int col = l & 15, kg = l >> 4;
            ushort h[8];
#pragma unroll
            for (int i = 0; i < 8; ++i) {
                int k = kc * 32 + kg * 8 + i;
                h[i] = bfb(w2[k * 256 + nt * 16 + col]);
            }
            uint4 r;
            r.x = h[0] | ((uint)h[1] << 16);
            r.y = h[2] | ((uint)h[3] << 16);
            r.z = h[4] | ((uint)h[5] << 16);
            r.w = h[6] | ((uint)h[7] << 16);
            wf2[e] = r;
        }
    }
}

// ---- k_prep1: CSR x4/block (blk<500, adj8) + extract + fc0s ---------------
__global__ __launch_bounds__(256) void k_prep1(const unsigned char* __restrict__ adj8,
                                               const float* __restrict__ d,
                                               const float* __restrict__ x,
                                               int* __restrict__ cnt,
                                               int* __restrict__ idx,
                                               float* __restrict__ val,
                                               int* __restrict__ sid,
                                               int* __restrict__ sid_last,
                                               uint4* __restrict__ feA,
                                               const float* __restrict__ w0,
                                               const float* __restrict__ b0,
                                               float* __restrict__ hp0,
                                               float* __restrict__ mu0,
                                               float* __restrict__ rstd0) {
    int blk = blockIdx.x;
    if (blk < 500) {
        int m = blk * 4 + (threadIdx.x >> 6);
        int lane = threadIdx.x & 63;
        const unsigned char* row8 = adj8 + (size_t)m * N;
        float dm = d[m];
        int base = 0;
        for (int c0 = 0; c0 < N; c0 += 64) {
            int c = c0 + lane;
            float a = 0.f;
            if (c < N) { a = (float)row8[c]; if (c == m) a += 1.0f; }
            bool pred = (a != 0.f);
            unsigned long long mask = __ballot(pred);
            int pos = base + __popcll(mask & ((1ull << lane) - 1ull));
            if (pred && pos < CAP) {
                idx[m * CAP + pos] = c;
                val[m * CAP + pos] = dm * d[c] * a;
            }
            base += (int)__popcll(mask);
        }
        if (lane == 0) cnt[m] = base < CAP ? base : CAP;
    } else if (blk < 500 + B) {
        int b = blk - 500, tid = threadIdx.x;
        const float* xb = x + (size_t)b * XROW;
        __shared__ float dss_sh[63];
        __shared__ float fe_sh[64][16];
        if (tid < S - 1) {
            int s_ = (int)xb[tid * 17 + 15];
            sid[b * (S - 1) + tid] = s_;
            dss_sh[tid] = d[s_];
        }
        if (tid == S - 1) sid_last[b] = (int)xb[(S - 1) * 17 + 15];
        if (tid >= 240 && tid < 256) fe_sh[63][tid - 240] = 0.f;   // zero pad
        __syncthreads();
        for (int i = tid; i < (S - 1) * 16; i += 256) {
            int t = i >> 4, f = i & 15;
            fe_sh[t][f] = dss_sh[t] * xb[t * 17 + (f < 15 ? f : 16)];
        }
        __syncthreads();
        if (tid < 128) {
            int kc = tid >> 6, l = tid & 63;
            int f = l & 15, tg = l >> 4;
            ushort h[8];
#pragma unroll
            for (int j = 0; j < 8; ++j)
                h[j] = bfb(fe_sh[kc * 32 + tg * 8 + j][f]);
            uint4 r;
            r.x = h[0] | ((uint)h[1] << 16);
            r.y = h[2] | ((uint)h[3] << 16);
            r.z = h[4] | ((uint)h[5] << 16);
            r.w = h[6] | ((uint)h[7] << 16);
            feA[(b * 2 + kc) * 64 + l] = r;
        }
    } else {
        // fused fc0 + batch stats: block = 2 channels x 128 batch
        int tid = threadIdx.x;
        int c = tid >> 7, b = tid & 127;
        int o = (blk - 500 - B) * 2 + c;
        const float* xr = x + (size_t)b * XROW + (S - 1) * 17;
        float acc = b0[o];
#pragma unroll
        for (int f = 0; f < 15; ++f) acc += xr[f] * w0[f * 512 + o];
        hp0[b * 512 + o] = acc;
        float s = acc, s2 = acc * acc;
        for (int off = 32; off > 0; off >>= 1) {
            s += __shfl_down(s, off);
            s2 += __shfl_down(s2, off);
        }
        __shared__ float rs[4], rs2[4];
        int wv = tid >> 6;
        if ((tid & 63) == 0) { rs[wv] = s; rs2[wv] = s2; }
        __syncthreads();
        if ((tid & 127) == 0) {
            float S1 = rs[c * 2] + rs[c * 2 + 1];
            float S2 = rs2[c * 2] + rs2[c * 2 + 1];
            float m = S1 * (1.f / B);
            float var = S2 * (1.f / B) - m * m;
            mu0[o] = m;
            rstd0[o] = rsqrtf(var + 1e-5f);
        }
    }
}

// ---------------- kernel 4: X1[b,p,:] = relu((Ahat X)[b,p] @ w1 + b1) ------
// adj8 gather (1B/lane, exact ints); fp8 X1; LDS-bounce transpose (union)
__global__ __launch_bounds__(256) void k_x1(const unsigned char* __restrict__ adj8,
                                            const float* __restrict__ d,
                                            const int* __restrict__ sid,
                                            const uint4* __restrict__ feA,
                                            const uint4* __restrict__ wfrag,
                                            const float* __restrict__ b1,
                                            unsigned char* __restrict__ X1) {
    __shared__ int sv[64];
    __shared__ float b1s[256];
    __shared__ __align__(16) union SU {
        ushort Ylds[64][40];     // 80B rows (phase 1 -> phase 2 hand-off)
        uint   Xs[4][16][68];    // epilogue transpose tile (after Ylds dead)
    } su;
    int b = blockIdx.y, p0 = blockIdx.x * 64, tid = threadIdx.x;
    b1s[tid] = b1[tid];
    if (tid < 63) sv[tid] = sid[b * 63 + tid];
    if (tid == 63) sv[63] = 0;
    __syncthreads();

    int l = tid & 63, wv = tid >> 6;
    int lm = l & 15, lg = l >> 4;
    int pt = p0 + wv * 16;
    int pcol = pt + lm;
    bool pv = (pcol < N);
    int pc = pv ? pcol : 0;

    s8v a1_0 = *(const s8v*)&feA[(b * 2 + 0) * 64 + l];
    s8v a1_1 = *(const s8v*)&feA[(b * 2 + 1) * 64 + l];

    int ss[16];
#pragma unroll
    for (int q = 0; q < 16; ++q)
        ss[q] = sv[(q >> 3) * 32 + lg * 8 + (q & 7)];
    float av[16];
#pragma unroll
    for (int q = 0; q < 16; ++q)
        av[q] = (float)adj8[(size_t)ss[q] * N + pc];
#pragma unroll
    for (int q = 0; q < 16; ++q) {
        av[q] = pv ? av[q] : 0.f;
        if (pcol == ss[q]) av[q] += 1.0f;
    }
    ushort h[16];
#pragma unroll
    for (int q = 0; q < 16; ++q) h[q] = bfb(av[q]);
    s8v b1f, b2f;
    {
        uint4 t0, t1;
        t0.x = h[0] | ((uint)h[1] << 16);  t0.y = h[2] | ((uint)h[3] << 16);
        t0.z = h[4] | ((uint)h[5] << 16);  t0.w = h[6] | ((uint)h[7] << 16);
        t1.x = h[8] | ((uint)h[9] << 16);  t1.y = h[10] | ((uint)h[11] << 16);
        t1.z = h[12] | ((uint)h[13] << 16); t1.w = h[14] | ((uint)h[15] << 16);
        b1f = *(s8v*)&t0; b2f = *(s8v*)&t1;
    }
    f4v D1 = (f4v){0.f, 0.f, 0.f, 0.f};
    D1 = __builtin_amdgcn_mfma_f32_16x16x32_bf16(a1_0, b1f, D1, 0, 0, 0);
    D1 = __builtin_amdgcn_mfma_f32_16x16x32_bf16(a1_1, b2f, D1, 0, 0, 0);
    float dp = d[pc] * (pv ? 1.f : 0.f);
    uint2 pk;
    pk.x = bfb(D1[0] * dp) | ((uint)bfb(D1[1] * dp) << 16);
    pk.y = bfb(D1[2] * dp) | ((uint)bfb(D1[3] * dp) << 16);
    *(uint2*)&su.Ylds[wv * 16 + lm][lg * 4] = pk;
    *(uint2*)&su.Ylds[wv * 16 + lm][16 + lg * 4] = make_uint2(0u, 0u);  // K-pad
    __syncthreads();

    s8v yf = *(const s8v*)&su.Ylds[wv * 16 + lm][lg * 8];   // B = Y^T frag
    __syncthreads();   // all yf read before Xs overwrites Ylds (union)
    f4v acc2[16];
#pragma unroll
    for (int ct = 0; ct < 16; ++ct) acc2[ct] = (f4v){0.f, 0.f, 0.f, 0.f};
#pragma unroll
    for (int ct = 0; ct < 16; ++ct) {
        s8v wfv = *(const s8v*)&wfrag[ct * 64 + l];         // A = W^T frag
        acc2[ct] = __builtin_amdgcn_mfma_f32_16x16x32_bf16(wfv, yf, acc2[ct], 0, 0, 0);
    }
    // epilogue: bias+relu+fp8-pack into per-wave LDS tile (transpose)
#pragma unroll
    for (int ct = 0; ct < 16; ++ct) {
        float4 bz = *(float4*)&b1s[ct * 16 + lg * 4];
        float v0 = acc2[ct][0] + bz.x; v0 = v0 > 0.f ? v0 : 0.f;
        float v1 = acc2[ct][1] + bz.y; v1 = v1 > 0.f ? v1 : 0.f;
        float v2 = acc2[ct][2] + bz.z; v2 = v2 > 0.f ? v2 : 0.f;
        float v3 = acc2[ct][3] + bz.w; v3 = v3 > 0.f ? v3 : 0.f;
        uint pk8 = (uint)__builtin_amdgcn_cvt_pk_fp8_f32(v0, v1, 0, false);
        pk8 = (uint)__builtin_amdgcn_cvt_pk_fp8_f32(v2, v3, (int)pk8, true);
        su.Xs[wv][lm][ct * 4 + lg] = pk8;
    }
    __syncthreads();
    {
        uint4* dstb = (uint4*)((uint*)X1 + ((size_t)b * N + p0 + wv * 16) * 64);
#pragma unroll
        for (int i = 0; i < 4; ++i) {
            int g = l + 64 * i;
            int r = g >> 4, c4 = g & 15;
            if (p0 + wv * 16 + r < N)
                dstb[g] = *(uint4*)&su.Xs[wv][r][c4 * 4];
        }
    }
}

// ---------------- kernel 5a: k_gather — fp8 agg out, 4-deep prefetch -------
__global__ __launch_bounds__(256) void k_gather(const int* __restrict__ cnt,
                                                const int* __restrict__ idxA,
                                                const float* __restrict__ valA,
                                                const int* __restrict__ sid_last,
                                                const unsigned char* __restrict__ X1,
                                                unsigned char* __restrict__ aggG) {
    __shared__ int   nns[JG];
    __shared__ int   ncn_s[JG];
    __shared__ int   nidx[JG][CAP];
    __shared__ float nval[JG][CAP];
    int b = blockIdx.y, j0 = blockIdx.x * JG, tid = threadIdx.x;
    int m = sid_last[b];
    int cj = cnt[m];
    if (tid < JG) {
        int j = j0 + tid;
        int n = idxA[m * CAP + (j < cj ? j : 0)];
        nns[tid] = n;
        ncn_s[tid] = (j < cj) ? cnt[n] : 0;
    }
    __syncthreads();
    for (int i = tid; i < JG * CAP; i += 256) {
        int jj = i >> 7, k = i & (CAP - 1);
        int n = nns[jj], c = ncn_s[jj];
        nidx[jj][k] = (k < c) ? idxA[n * CAP + k] : 0;
        nval[jj][k] = (k < c) ? valA[n * CAP + k] : 0.f;
    }
    __syncthreads();
    int lane = tid & 63;
    int w = __builtin_amdgcn_readfirstlane(tid >> 6);
    int la = w * 2, lb = la + 1;
    const uint* X1bl = (const uint*)X1 + (size_t)b * N * 64 + lane;
    int cA = ncn_s[la], cB = ncn_s[lb];
    int cmax = cA > cB ? cA : cB;
    float aA0 = 0.f, aA1 = 0.f, aA2 = 0.f, aA3 = 0.f;
    float aB0 = 0.f, aB1 = 0.f, aB2 = 0.f, aB3 = 0.f;
    if (cmax > 0) {
        uint uA0, uA1, uA2, uA3, uB0, uB1, uB2, uB3;
        float vA0, vA1, vA2, vA3, vB0, vB1, vB2, vB3;
        uA0 = X1bl[(size_t)nidx[la][0] * 64]; vA0 = nval[la][0];
        uA1 = X1bl[(size_t)nidx[la][1] * 64]; vA1 = nval[la][1];
        uA2 = X1bl[(size_t)nidx[la][2] * 64]; vA2 = nval[la][2];
        uA3 = X1bl[(size_t)nidx[la][3] * 64]; vA3 = nval[la][3];
        uB0 = X1bl[(size_t)nidx[lb][0] * 64]; vB0 = nval[lb][0];
        uB1 = X1bl[(size_t)nidx[lb][1] * 64]; vB1 = nval[lb][1];
        uB2 = X1bl[(size_t)nidx[lb][2] * 64]; vB2 = nval[lb][2];
        uB3 = X1bl[(size_t)nidx[lb][3] * 64]; vB3 = nval[lb][3];
        int c4 = (cmax + 3) & ~3;
        for (int k = 0; k < c4; k += 4) {
            uint cA0 = uA0, cA1 = uA1, cA2 = uA2, cA3 = uA3;
            uint cB0 = uB0, cB1 = uB1, cB2 = uB2, cB3 = uB3;
            float wA0 = vA0, wA1 = vA1, wA2 = vA2, wA3 = vA3;
            float wB0 = vB0, wB1 = vB1, wB2 = vB2, wB3 = vB3;
            int k4 = k + 4; k4 = k4 < CAP ? k4 : CAP - 1;
            int k5 = k + 5; k5 = k5 < CAP ? k5 : CAP - 1;
            int k6 = k + 6; k6 = k6 < CAP ? k6 : CAP - 1;
            int k7 = k + 7; k7 = k7 < CAP ? k7 : CAP - 1;
            uA0 = X1bl[(size_t)nidx[la][k4] * 64]; vA0 = nval[la][k4];
            uA1 = X1bl[(size_t)nidx[la][k5] * 64]; vA1 = nval[la][k5];
            uA2 = X1bl[(size_t)nidx[la][k6] * 64]; vA2 = nval[la][k6];
            uA3 = X1bl[(size_t)nidx[la][k7] * 64]; vA3 = nval[la][k7];
            uB0 = X1bl[(size_t)nidx[lb][k4] * 64]; vB0 = nval[lb][k4];
            uB1 = X1bl[(size_t)nidx[lb][k5] * 64]; vB1 = nval[lb][k5];
            uB2 = X1bl[(size_t)nidx[lb][k6] * 64]; vB2 = nval[lb][k6];
            uB3 = X1bl[(size_t)nidx[lb][k7] * 64]; vB3 = nval[lb][k7];
            f2v lo, hi;
            lo = __builtin_amdgcn_cvt_pk_f32_fp8((int)cA0, false);
            hi = __builtin_amdgcn_cvt_pk_f32_fp8((int)cA0, true);
            aA0 += wA0 * lo.x; aA1 += wA0 * lo.y; aA2 += wA0 * hi.x; aA3 += wA0 * hi.y;
            lo = __builtin_amdgcn_cvt_pk_f32_fp8((int)cA1, false);
            hi = __builtin_amdgcn_cvt_pk_f32_fp8((int)cA1, true);
            aA0 += wA1 * lo.x; aA1 += wA1 * lo.y; aA2 += wA1 * hi.x; aA3 += wA1 * hi.y;
            lo = __builtin_amdgcn_cvt_pk_f32_fp8((int)cA2, false);
            hi = __builtin_amdgcn_cvt_pk_f32_fp8((int)cA2, true);
            aA0 += wA2 * lo.x; aA1 += wA2 * lo.y; aA2 += wA2 * hi.x; aA3 += wA2 * hi.y;
            lo = __builtin_amdgcn_cvt_pk_f32_fp8((int)cA3, false);
            hi = __builtin_amdgcn_cvt_pk_f32_fp8((int)cA3, true);
            aA0 += wA3 * lo.x; aA1 += wA3 * lo.y; aA2 += wA3 * hi.x; aA3 += wA3 * hi.y;
            lo = __builtin_amdgcn_cvt_pk_f32_fp8((int)cB0, false);
            hi = __builtin_amdgcn_cvt_pk_f32_fp8((int)cB0, true);
            aB0 += wB0 * lo.x; aB1 += wB0 * lo.y; aB2 += wB0 * hi.x; aB3 += wB0 * hi.y;
            lo = __builtin_amdgcn_cvt_pk_f32_fp8((int)cB1, false);
            hi = __builtin_amdgcn_cvt_pk_f32_fp8((int)cB1, true);
            aB0 += wB1 * lo.x; aB1 += wB1 * lo.y; aB2 += wB1 * hi.x; aB3 += wB1 * hi.y;
            lo = __builtin_amdgcn_cvt_pk_f32_fp8((int)cB2, false);
            hi = __builtin_amdgcn_cvt_pk_f32_fp8((int)cB2, true);
            aB0 += wB2 * lo.x; aB1 += wB2 * lo.y; aB2 += wB2 * hi.x; aB3 += wB2 * hi.y;
            lo = __builtin_amdgcn_cvt_pk_f32_fp8((int)cB3, false);
            hi = __builtin_amdgcn_cvt_pk_f32_fp8((int)cB3, true);
            aB0 += wB3 * lo.x; aB1 += wB3 * lo.y; aB2 += wB3 * hi.x; aB3 += wB3 * hi.y;
        }
    }
    uint pkA = (uint)__builtin_amdgcn_cvt_pk_fp8_f32(aA0, aA1, 0, false);
    pkA = (uint)__builtin_amdgcn_cvt_pk_fp8_f32(aA2, aA3, (int)pkA, true);
    uint pkB = (uint)__builtin_amdgcn_cvt_pk_fp8_f32(aB0, aB1, 0, false);
    pkB = (uint)__builtin_amdgcn_cvt_pk_fp8_f32(aB2, aB3, (int)pkB, true);
    uint* ag = (uint*)aggG;
    ag[((size_t)b * CAP + j0 + la) * 64 + lane] = pkA;
    ag[((size_t)b * CAP + j0 + lb) * 64 + lane] = pkB;
}

// ---------------- kernel 5b: k_x2g — fp8 agg in, MFMA + j-reduction --------
__global__ __launch_bounds__(256) void k_x2g(const int* __restrict__ cnt,
                                             const int* __restrict__ sid_last,
                                             const float* __restrict__ valA,
                                             const unsigned char* __restrict__ aggG,
                                             const uint4* __restrict__ w2f,
                                             const float* __restrict__ b2,
                                             float* __restrict__ gaggP) {
    __shared__ ushort agg[JT][264];   // 528B row stride (bf16, unpacked)
    __shared__ float vs[JT];
    int b = blockIdx.y, j0 = blockIdx.x * JT, tid = threadIdx.x;
    int m = sid_last[b];
    int cj = cnt[m];
    if (j0 >= cj) return;
    int nj = cj - j0; if (nj > JT) nj = JT;
    if (tid < JT) vs[tid] = (tid < nj) ? valA[m * CAP + j0 + tid] : 0.f;
    {
        const uint* src = (const uint*)aggG + ((size_t)b * CAP + j0) * 64;
        for (int i = tid; i < JT * 64; i += 256) {
            int row = i >> 6, ln = i & 63;
            uint u8 = src[(size_t)row * 64 + ln];
            f2v lo = __builtin_amdgcn_cvt_pk_f32_fp8((int)u8, false);
            f2v hi = __builtin_amdgcn_cvt_pk_f32_fp8((int)u8, true);
            uint2 pk;
            pk.x = bfb(lo.x) | ((uint)bfb(lo.y) << 16);
            pk.y = bfb(hi.x) | ((uint)bfb(hi.y) << 16);
            *(uint2*)&agg[row][ln * 4] = pk;
        }
    }
    __syncthreads();
    int lane = tid & 63;
    int w = __builtin_amdgcn_readfirstlane(tid >> 6);
    int col = lane & 15, rg = lane >> 4;
    s8v af[8];
#pragma unroll
    for (int kc = 0; kc < 8; ++kc)
        af[kc] = *(const s8v*)&agg[col][kc * 32 + rg * 8];
    float* outp = gaggP + ((size_t)b * 8 + blockIdx.x) * 256;
#pragma unroll
    for (int t = 0; t < 4; ++t) {
        int nt = w * 4 + t;
        f4v acc = (f4v){0.f, 0.f, 0.f, 0.f};
#pragma unroll
        for (int kc = 0; kc < 8; ++kc) {
            s8v bf = *(const s8v*)&w2f[(nt * 8 + kc) * 64 + lane];
            acc = __builtin_amdgcn_mfma_f32_16x16x32_bf16(af[kc], bf, acc, 0, 0, 0);
        }
        float bv = b2[nt * 16 + col];
        float p = 0.f;
#pragma unroll
        for (int i = 0; i < 4; ++i) {
            float vv = acc[i] + bv;
            vv = vv > 0.f ? vv : 0.f;
            p += vs[rg * 4 + i] * vv;
        }
        p += __shfl_xor(p, 16);
        p += __shfl_xor(p, 32);
        if (lane < 16) outp[nt * 16 + col] = p;
    }
}

// ---------------- k_gmm — g = relu(sum(gaggP) @ w3 + b3) -------------------
__global__ __launch_bounds__(256) void k_gmm(const int* __restrict__ cnt,
                                             const int* __restrict__ sid_last,
                                             const float* __restrict__ gaggP,
                                             const float* __restrict__ w3,
                                             const float* __restrict__ b3,
                                             float* __restrict__ g) {
    int b = blockIdx.x, ot = blockIdx.y, tid = threadIdx.x;
    __shared__ float h[256];
    {
        int m = sid_last[b];
        int cj = cnt[m];
        int nq = (cj + JT - 1) / JT;
        const float* p = gaggP + (size_t)b * 8 * 256 + tid;
        float s = 0.f;
        for (int q = 0; q < nq; ++q) s += p[q * 256];
        h[tid] = s;
    }
    __syncthreads();
    int q  = tid & 31;       // output quad
    int kg = tid >> 5;       // 0..7, K-group of 32
    const float4* w4 = (const float4*)w3;     // 128 quads per k-row
    int wq = ot * 32 + q;
    float4 acc = {0.f, 0.f, 0.f, 0.f};
    for (int k = kg * 32; k < kg * 32 + 32; ++k) {
        float hk = h[k];
        float4 w = w4[(size_t)k * 128 + wq];
        acc.x += hk * w.x; acc.y += hk * w.y; acc.z += hk * w.z; acc.w += hk * w.w;
    }
    __shared__ float4 red[8][32];
    red[kg][q] = acc;
    __syncthreads();
    if (tid < 32) {
        float4 s = red[0][tid];
#pragma unroll
        for (int gr = 1; gr < 8; ++gr) {
            float4 r = red[gr][tid];
            s.x += r.x; s.y += r.y; s.z += r.z; s.w += r.w;
        }
        int ob = ot * 128 + tid * 4;
        s.x += b3[ob];     s.x = s.x > 0.f ? s.x : 0.f;
        s.y += b3[ob + 1]; s.y = s.y > 0.f ? s.y : 0.f;
        s.z += b3[ob + 2]; s.z = s.z > 0.f ? s.z : 0.f;
        s.w += b3[ob + 3]; s.w = s.w > 0.f ? s.w : 0.f;
        *(float4*)&g[(size_t)b * 512 + ob] = s;
    }
}

// ---------------- k_bn1w: widened batch-norm stats for hp1 (grid 16) -------
__global__ __launch_bounds__(256) void k_bn1w(const float* __restrict__ h,
                                              float* __restrict__ mu,
                                              float* __restrict__ rstd) {
    int tid = threadIdx.x;
    int o = blockIdx.x * 32 + (tid & 31);
    int bg = tid >> 5;   // 0..7
    float s = 0.f, s2 = 0.f;
    for (int b = bg * 16; b < bg * 16 + 16; ++b) {
        float v = h[b * 512 + o];
        s += v; s2 += v * v;
    }
    __shared__ float rs[8][32], rs2[8][32];
    rs[bg][tid & 31] = s; rs2[bg][tid & 31] = s2;
    __syncthreads();
    if (tid < 32) {
        float S1 = 0.f, S2 = 0.f;
#pragma unroll
        for (int g2 = 0; g2 < 8; ++g2) { S1 += rs[g2][tid]; S2 += rs2[g2][tid]; }
        float m = S1 * (1.f / B);
        float var = S2 * (1.f / B) - m * m;
        mu[blockIdx.x * 32 + tid] = m;
        rstd[blockIdx.x * 32 + tid] = rsqrtf(var + 1e-5f);
    }
}

// ---------------- kernel 9: hp1 = [leaky(bn(hp0)), g] @ w1 + b1 ------------
__global__ __launch_bounds__(256) void k_fc1(const float* __restrict__ hp0,
                                             const float* __restrict__ mu0,
                                             const float* __restrict__ rstd0,
                                             const float* __restrict__ gam,
                                             const float* __restrict__ bet,
                                             const float* __restrict__ gbuf,
                                             const float* __restrict__ w1,
                                             const float* __restrict__ b1,
                                             float* __restrict__ hp1) {
    int b = blockIdx.x, ot = blockIdx.y, tid = threadIdx.x;
    __shared__ float h[1024];
    for (int o = tid; o < 512; o += 256) {
        float v = hp0[b * 512 + o];
        v = gam[o] * (v - mu0[o]) * rstd0[o] + bet[o];
        h[o] = v >= 0.f ? v : 0.01f * v;
        h[512 + o] = gbuf[(size_t)b * 512 + o];
    }
    __syncthreads();
    int q  = tid & 31;
    int kg = tid >> 5;
    const float4* w4 = (const float4*)w1;
    int wq = ot * 32 + q;
    float4 acc = {0.f, 0.f, 0.f, 0.f};
    for (int k = kg * 128; k < kg * 128 + 128; ++k) {
        float hk = h[k];
        float4 w = w4[(size_t)k * 128 + wq];
        acc.x += hk * w.x; acc.y += hk * w.y; acc.z += hk * w.z; acc.w += hk * w.w;
    }
    __shared__ float4 red[8][32];
    red[kg][q] = acc;
    __syncthreads();
    if (tid < 32) {
        float4 s = red[0][tid];
#pragma unroll
        for (int gr = 1; gr < 8; ++gr) {
            float4 r = red[gr][tid];
            s.x += r.x; s.y += r.y; s.z += r.z; s.w += r.w;
        }
        int ob = ot * 128 + tid * 4;
        s.x += b1[ob]; s.y += b1[ob + 1]; s.z += b1[ob + 2]; s.w += b1[ob + 3];
        *(float4*)&hp1[b * 512 + ob] = s;
    }
}

// ---------------- kernel 11: out = sigmoid(leaky(bn(hp1)) @ w2 + b2) -------
__global__ __launch_bounds__(64) void k_out(const float* __restrict__ hp1,
                                            const float* __restrict__ mu1,
                                            const float* __restrict__ rstd1,
                                            const float* __restrict__ gam,
                                            const float* __restrict__ bet,
                                            const float* __restrict__ w2,
                                            const float* __restrict__ b2,
                                            float* __restrict__ out) {
    int b = blockIdx.x, lane = threadIdx.x;
    float acc = 0.f;
    for (int o = lane; o < 512; o += 64) {
        float v = hp1[b * 512 + o];
        v = gam[o] * (v - mu1[o]) * rstd1[o] + bet[o];
        v = v >= 0.f ? v : 0.01f * v;
        acc += v * w2[o];
    }
    for (int off = 32; off > 0; off >>= 1) acc += __shfl_down(acc, off);
    if (lane == 0) out[b] = 1.f / (1.f + expf(-(acc + b2[0])));
}

static inline size_t align256(size_t x) { return (x + 255) & ~(size_t)255; }

extern "C" void kernel_launch(void* const* d_in, const int* in_sizes, int n_in,
                              void* d_out, int out_size, void* d_ws, size_t ws_size,
                              hipStream_t stream) {
    const float* x     = (const float*)d_in[0];
    const float* adj   = (const float*)d_in[1];
    const float* w_gc1 = (const float*)d_in[2];
    const float* b_gc1 = (const float*)d_in[3];
    const float* w_gc2 = (const float*)d_in[4];
    const float* b_gc2 = (const float*)d_in[5];
    const float* w_gc3 = (const float*)d_in[6];
    const float* b_gc3 = (const float*)d_in[7];
    const float* w_fc0 = (const float*)d_in[8];
    const float* b_fc0 = (const float*)d_in[9];
    const float* g_fc0 = (const float*)d_in[10];
    const float* be_fc0= (const float*)d_in[11];
    const float* w_fc1 = (const float*)d_in[12];
    const float* b_fc1 = (const float*)d_in[13];
    const float* g_fc1 = (const float*)d_in[14];
    const float* be_fc1= (const float*)d_in[15];
    const float* w_fc2 = (const float*)d_in[16];
    const float* b_fc2 = (const float*)d_in[17];

    char* wsp = (char*)d_ws;
    size_t off = 0;
    auto alloc = [&](size_t bytes) { void* p = wsp + off; off = align256(off + bytes); return p; };
    float* d_deg   = (float*)alloc((size_t)N * 4);
    unsigned char* adj8 = (unsigned char*)alloc((size_t)N * N);
    int*   sid     = (int*)  alloc((size_t)B * 63 * 4);
    int*   sidl    = (int*)  alloc((size_t)B * 4);
    uint4* feA     = (uint4*)alloc((size_t)B * 2 * 64 * 16);
    uint4* wfrag   = (uint4*)alloc((size_t)1024 * 16);
    uint4* w2frag  = (uint4*)alloc((size_t)8192 * 16);
    int*   csr_cnt = (int*)  alloc((size_t)N * 4);
    int*   csr_idx = (int*)  alloc((size_t)N * CAP * 4);
    float* csr_val = (float*)alloc((size_t)N * CAP * 4);
    unsigned char* X1   = (unsigned char*)alloc((size_t)B * N * 256);
    unsigned char* aggG = (unsigned char*)alloc((size_t)B * CAP * 256);
    float* gaggP   = (float*)alloc((size_t)B * 8 * 256 * 4);
    float* gbuf    = (float*)alloc((size_t)B * 512 * 4);
    float* hp0     = (float*)alloc((size_t)B * 512 * 4);
    float* mu0     = (float*)alloc(512 * 4);
    float* rstd0   = (float*)alloc(512 * 4);
    float* hp1     = (float*)alloc((size_t)B * 512 * 4);
    float* mu1     = (float*)alloc(512 * 4);
    float* rstd1   = (float*)alloc(512 * 4);

    k_prep0 <<<N + 36, 256, 0, stream>>>(adj, d_deg, adj8, w_gc1, w_gc2, wfrag, w2frag);
    k_prep1 <<<500 + B + 256, 256, 0, stream>>>(adj8, d_deg, x, csr_cnt, csr_idx, csr_val,
                                                sid, sidl, feA, w_fc0, b_fc0, hp0, mu0, rstd0);
    k_x1    <<<dim3(32, B), 256, 0, stream>>>(adj8, d_deg, sid, feA, wfrag, b_gc1, X1);
    k_gather<<<dim3(CAP / JG, B), 256, 0, stream>>>(csr_cnt, csr_idx, csr_val, sidl, X1, aggG);
    k_x2g   <<<dim3(CAP / JT, B), 256, 0, stream>>>(csr_cnt, sidl, csr_val, aggG, w2frag, b_gc2, gaggP);
    k_gmm   <<<dim3(B, 4), 256, 0, stream>>>(csr_cnt, sidl, gaggP, w_gc3, b_gc3, gbuf);
    k_fc1   <<<dim3(B, 4), 256, 0, stream>>>(hp0, mu0, rstd0, g_fc0, be_fc0, gbuf, w_fc1, b_fc1, hp1);
    k_bn1w  <<<16, 256, 0, stream>>>(hp1, mu1, rstd1);
    k_out   <<<B, 64, 0, stream>>>(hp1, mu1, rstd1, g_fc1, be_fc1, w_fc2, b_fc2, (float*)d_out);
}